// Round 7
// baseline (23587.863 us; speedup 1.0000x reference)
//
#include <hip/hip_runtime.h>
#include <cmath>

// RSSM scan: B=16, T=64, A=6, E=12288, DET=4096, HID=1024, S=32, D=32
// fp32 throughout (argmax stability). Deterministic fixed-order reductions.
// 5 launches/step: img1(fused fin) -> GRU gemm -> red -> obs(fused gate+fin) -> post(fused sample).
// Cross-block fusion via threadfence + device atomic counter (last block finishes).

#define B 16
#define T_STEPS 64
#define A_DIM 6
#define E_DIM 12288
#define DET 4096
#define HID 1024
#define SD 1024
#define OUT_C 8192
#define OUT_RSTRIDE (T_STEPS * OUT_C)

typedef float f2v __attribute__((ext_vector_type(2)));
typedef float f4v __attribute__((ext_vector_type(4)));

// ---------------- block reduce (deterministic) ----------------
__device__ __forceinline__ float block_sum(float v, float* red, int nw) {
#pragma unroll
  for (int m = 32; m >= 1; m >>= 1) v += __shfl_xor(v, m, 64);
  int wid = threadIdx.x >> 6;
  if ((threadIdx.x & 63) == 0) red[wid] = v;
  __syncthreads();
  if (wid == 0) {
    float s = ((int)threadIdx.x < nw) ? red[threadIdx.x] : 0.0f;
#pragma unroll
    for (int m = 8; m >= 1; m >>= 1) s += __shfl_xor(s, m, 16);
    if (threadIdx.x == 0) red[0] = s;
  }
  __syncthreads();
  float out = red[0];
  __syncthreads();
  return out;
}

__global__ __launch_bounds__(1024) void k_tanh(const float* __restrict__ w, float* __restrict__ o) {
  int i = blockIdx.x * 1024 + threadIdx.x;
  if (i < DET) o[i] = tanhf(w[i]);
}

// ---------------- prep (t=0 only) ----------------
__global__ __launch_bounds__(256) void k_prep(
    const float* __restrict__ isf, const float* __restrict__ pa, int t,
    const float* __restrict__ stoch_prev,
    const float* __restrict__ deter_prev, long deter_prev_stride,
    const float* __restrict__ init_stoch, const float* __restrict__ init_deter_row,
    float* __restrict__ stoch_in, float* __restrict__ deter_in, float* __restrict__ a_eff) {
  int r = blockIdx.x;
  float f = isf[r * T_STEPS + t];
  float omf = 1.0f - f;
  for (int c = threadIdx.x; c < SD; c += 256)
    stoch_in[r * SD + c] = stoch_prev[r * SD + c] * omf + init_stoch[r * SD + c] * f;
  for (int c = threadIdx.x; c < DET; c += 256)
    deter_in[r * DET + c] = deter_prev[(long)r * deter_prev_stride + c] * omf + init_deter_row[c] * f;
  if ((int)threadIdx.x < A_DIM) {
    float a = pa[(r * T_STEPS + t) * A_DIM + threadIdx.x];
    a = a * (1.0f / fmaxf(fabsf(a), 1.0f));
    a_eff[r * 8 + threadIdx.x] = a * omf;
  }
}

// ---------------- K-split GEMM (round-3 body; init + GRU) ----------------
struct GemmArgs {
  const float* A0; long sA0; int cA0;
  const float* A1; long sA1;
  const float* W; int N; int Ktot; int KS; int nsplit;
  float* P;
};

template <bool NT>
__global__ __launch_bounds__(256) void k_gemm(GemmArgs g) {
  const int tid = threadIdx.x;
  const int c0 = blockIdx.x * 512 + tid * 2;
  const int k0 = (int)blockIdx.y * g.KS;
  __shared__ float in_s[16][64];
  float acc[16][2];
#pragma unroll
  for (int r = 0; r < 16; r++) { acc[r][0] = 0.f; acc[r][1] = 0.f; }
  for (int kb = 0; kb < g.KS; kb += 64) {
    const int kbase = k0 + kb;
#pragma unroll
    for (int j = 0; j < 4; j++) {
      int ii = tid + j * 256;
      int r = ii >> 6, kk = ii & 63;
      int k = kbase + kk;
      float v = 0.f;
      if (k < g.cA0) v = g.A0[(long)r * g.sA0 + k];
      else if (k < g.Ktot) v = g.A1[(long)r * g.sA1 + (k - g.cA0)];
      in_s[r][kk] = v;
    }
    __syncthreads();
    if (kbase + 64 <= g.Ktot) {
      const float* wp = g.W + (size_t)kbase * g.N + c0;
#pragma unroll 4
      for (int kk = 0; kk < 64; kk++) {
        f2v w = NT ? __builtin_nontemporal_load((const f2v*)wp) : *(const f2v*)wp;
        wp += g.N;
#pragma unroll
        for (int r = 0; r < 16; r++) {
          acc[r][0] += in_s[r][kk] * w[0]; acc[r][1] += in_s[r][kk] * w[1];
        }
      }
    } else {
#pragma unroll 4
      for (int kk = 0; kk < 64; kk++) {
        int krow = kbase + kk; if (krow >= g.Ktot) krow = g.Ktot - 1;
        const f2v w = *(const f2v*)(g.W + (size_t)krow * g.N + c0);
#pragma unroll
        for (int r = 0; r < 16; r++) {
          acc[r][0] += in_s[r][kk] * w[0]; acc[r][1] += in_s[r][kk] * w[1];
        }
      }
    }
    __syncthreads();
  }
#pragma unroll
  for (int r = 0; r < 16; r++)
    *(f2v*)(g.P + ((size_t)blockIdx.y * 16 + r) * g.N + c0) = f2v{acc[r][0], acc[r][1]};
}

// ---------------- finish (init chain): sum partials + LN + silu ----------------
__global__ __launch_bounds__(1024) void k_fin(
    const float* __restrict__ P, int nP,
    const float* __restrict__ gv, const float* __restrict__ bv,
    float* __restrict__ o) {
  int r = blockIdx.x, c = threadIdx.x;
  __shared__ float red[18];
  float v = 0.0f;
  for (int ks = 0; ks < nP; ks++) v += P[((size_t)ks * 16 + r) * HID + c];
  float m = block_sum(v, red, 16) * (1.0f / (float)HID);
  float d = v - m;
  float var = block_sum(d * d, red, 16) * (1.0f / (float)HID);
  float rs = 1.0f / sqrtf(var + 1e-3f);
  float y = d * rs * gv[c] + bv[c];
  float s = 1.0f / (1.0f + expf(-y));
  o[r * HID + c] = y * s;
}

// ---------------- init sample (mode) ----------------
__global__ __launch_bounds__(1024) void k_samp_init(
    const float* __restrict__ P, int nP, const float* __restrict__ bb,
    float* __restrict__ st) {
  int r = blockIdx.x, c = threadIdx.x;
  float acc = bb[c];
  for (int ks = 0; ks < nP; ks++) acc += P[((size_t)ks * 16 + r) * SD + c];
  int d = c & 31;
  float mx = acc;
#pragma unroll
  for (int m = 16; m >= 1; m >>= 1) mx = fmaxf(mx, __shfl_xor(mx, m, 32));
  float e = expf(acc - mx);
  float se = e;
#pragma unroll
  for (int m = 16; m >= 1; m >>= 1) se += __shfl_xor(se, m, 32);
  float p = 0.99f * (e / se) + 3.125e-4f;
  float by = p; int bi = d;
#pragma unroll
  for (int m = 16; m >= 1; m >>= 1) {
    float oy = __shfl_xor(by, m, 32);
    int oi = __shfl_xor(bi, m, 32);
    if (oy > by || (oy == by && oi < bi)) { by = oy; bi = oi; }
  }
  float oh = (d == bi) ? 1.0f : 0.0f;
  st[r * SD + c] = (oh + p) - p;
}

// ---------------- tiled GEMM: out[M x 1024] = A[M x K] @ Bw[K x 1024] (+bias) ----------
__global__ __launch_bounds__(256) void k_mm(const float* __restrict__ A, long lda,
                                            const float* __restrict__ Bw, int K,
                                            float* __restrict__ out, long ldo,
                                            const float* __restrict__ bias) {
  __shared__ float As[32][68];
  __shared__ float Bs[32][68];
  const int tid = threadIdx.x;
  const int tx = tid & 15, ty = tid >> 4;
  const int row0 = blockIdx.y * 64, col0 = blockIdx.x * 64;
  const int ar = tid >> 2, ak = (tid & 3) * 8;
  const int bk = tid >> 4, bc = (tid & 15) * 4;
  float acc[4][4] = {};
  const float* ap = A + (size_t)(row0 + ar) * lda + ak;
  const float* bp = Bw + (size_t)bk * HID + col0 + bc;
  for (int k0 = 0; k0 < K; k0 += 32) {
    float4 a0 = *(const float4*)(ap + k0);
    float4 a1 = *(const float4*)(ap + k0 + 4);
    float4 b0 = *(const float4*)(bp + (size_t)k0 * HID);
    float4 b1 = *(const float4*)(bp + (size_t)(k0 + 16) * HID);
    __syncthreads();
    As[ak + 0][ar] = a0.x; As[ak + 1][ar] = a0.y; As[ak + 2][ar] = a0.z; As[ak + 3][ar] = a0.w;
    As[ak + 4][ar] = a1.x; As[ak + 5][ar] = a1.y; As[ak + 6][ar] = a1.z; As[ak + 7][ar] = a1.w;
    *(float4*)&Bs[bk][bc] = b0;
    *(float4*)&Bs[bk + 16][bc] = b1;
    __syncthreads();
#pragma unroll
    for (int kk = 0; kk < 32; kk++) {
      float4 av = *(const float4*)&As[kk][ty * 4];
      float4 bv = *(const float4*)&Bs[kk][tx * 4];
      acc[0][0] += av.x * bv.x; acc[0][1] += av.x * bv.y; acc[0][2] += av.x * bv.z; acc[0][3] += av.x * bv.w;
      acc[1][0] += av.y * bv.x; acc[1][1] += av.y * bv.y; acc[1][2] += av.y * bv.z; acc[1][3] += av.y * bv.w;
      acc[2][0] += av.z * bv.x; acc[2][1] += av.z * bv.y; acc[2][2] += av.z * bv.z; acc[2][3] += av.z * bv.w;
      acc[3][0] += av.w * bv.x; acc[3][1] += av.w * bv.y; acc[3][2] += av.w * bv.z; acc[3][3] += av.w * bv.w;
    }
  }
#pragma unroll
  for (int i = 0; i < 4; i++) {
    float4 o;
    int col = col0 + tx * 4;
    o.x = acc[i][0] + (bias ? bias[col + 0] : 0.f);
    o.y = acc[i][1] + (bias ? bias[col + 1] : 0.f);
    o.z = acc[i][2] + (bias ? bias[col + 2] : 0.f);
    o.w = acc[i][3] + (bias ? bias[col + 3] : 0.f);
    *(float4*)(out + (size_t)(row0 + ty * 4 + i) * ldo + col) = o;
  }
}

// ---------------- deferred: per-row LN + silu in place ----------------
__global__ __launch_bounds__(256) void k_ln_rows(float* __restrict__ h,
                                                 const float* __restrict__ gv,
                                                 const float* __restrict__ bv) {
  int row = blockIdx.x, c0 = threadIdx.x * 4;
  __shared__ float red[18];
  float4 v = *(const float4*)(h + (size_t)row * HID + c0);
  float lsum = (v.x + v.y) + (v.z + v.w);
  float m = block_sum(lsum, red, 4) * (1.0f / (float)HID);
  float dx = v.x - m, dy = v.y - m, dz = v.z - m, dw = v.w - m;
  float lv = (dx * dx + dy * dy) + (dz * dz + dw * dw);
  float var = block_sum(lv, red, 4) * (1.0f / (float)HID);
  float rs = 1.0f / sqrtf(var + 1e-3f);
  float4 o;
  float y0 = dx * rs * gv[c0] + bv[c0];         o.x = y0 / (1.0f + expf(-y0));
  float y1 = dy * rs * gv[c0 + 1] + bv[c0 + 1]; o.y = y1 / (1.0f + expf(-y1));
  float y2 = dz * rs * gv[c0 + 2] + bv[c0 + 2]; o.z = y2 / (1.0f + expf(-y2));
  float y3 = dw * rs * gv[c0 + 3] + bv[c0 + 3]; o.w = y3 / (1.0f + expf(-y3));
  *(float4*)(h + (size_t)row * HID + c0) = o;
}

// ---------------- deferred: batched prior sample (logits in out+7168) ----------------
__global__ __launch_bounds__(1024) void k_samp_prior(float* __restrict__ out,
                                                     const float* __restrict__ gum) {
  int m = blockIdx.x, c = threadIdx.x;
  float lp = out[(size_t)m * OUT_C + 7168 + c];
  int d = c & 31;
  float mx = lp;
#pragma unroll
  for (int mm = 16; mm >= 1; mm >>= 1) mx = fmaxf(mx, __shfl_xor(mx, mm, 32));
  float e = expf(lp - mx);
  float se = e;
#pragma unroll
  for (int mm = 16; mm >= 1; mm >>= 1) se += __shfl_xor(se, mm, 32);
  float p = 0.99f * (e / se) + 3.125e-4f;
  float y = logf(p) + gum[(size_t)m * SD + c];
  float by = y; int bi = d;
#pragma unroll
  for (int mm = 16; mm >= 1; mm >>= 1) {
    float oy = __shfl_xor(by, mm, 32);
    int oi = __shfl_xor(bi, mm, 32);
    if (oy > by || (oy == by && oi < bi)) { by = oy; bi = oi; }
  }
  float oh = (d == bi) ? 1.0f : 0.0f;
  out[(size_t)m * OUT_C + 6144 + c] = (oh + p) - p;
}

// ---------------- GRU stage-1 reduce: sum splits + (sum, sumsq) per chunk ----------
__global__ __launch_bounds__(256) void k_red(const float* __restrict__ P, int nP,
                                             float* __restrict__ S,
                                             float* __restrict__ red_s, float* __restrict__ red_q) {
  int chunk = blockIdx.x, r = blockIdx.y;
  int c = chunk * 1024 + threadIdx.x * 4;
  float4 s = {0, 0, 0, 0};
  for (int ks = 0; ks < nP; ks++) {
    float4 v = *(const float4*)(P + ((size_t)ks * 16 + r) * (3 * DET) + c);
    s.x += v.x; s.y += v.y; s.z += v.z; s.w += v.w;
  }
  *(float4*)(S + (size_t)r * (3 * DET) + c) = s;
  float sx = (s.x + s.y) + (s.z + s.w);
  float sq = (s.x * s.x + s.y * s.y) + (s.z * s.z + s.w * s.w);
  __shared__ float rbuf[8];
#pragma unroll
  for (int m = 32; m >= 1; m >>= 1) { sx += __shfl_xor(sx, m, 64); sq += __shfl_xor(sq, m, 64); }
  int wid = threadIdx.x >> 6;
  if ((threadIdx.x & 63) == 0) { rbuf[wid] = sx; rbuf[4 + wid] = sq; }
  __syncthreads();
  if (threadIdx.x == 0) {
    red_s[r * 12 + chunk] = (rbuf[0] + rbuf[1]) + (rbuf[2] + rbuf[3]);
    red_q[r * 12 + chunk] = (rbuf[4] + rbuf[5]) + (rbuf[6] + rbuf[7]);
  }
}

// ================ fused kernels (threadfence + counter, last block finishes) ================

// ---- img1: GEMM partials (34 blocks) + last-block LN+silu -> x ----
__global__ __launch_bounds__(256) void k_img1f(
    const float* __restrict__ stoch_in, const float* __restrict__ a_eff,
    const float* __restrict__ W, const float* __restrict__ gv, const float* __restrict__ bv,
    float* __restrict__ P, float* __restrict__ xout, unsigned int* __restrict__ cnt) {
  const int tid = threadIdx.x;
  const int c0 = blockIdx.x * 512 + tid * 2;
  const int kbase = (int)blockIdx.y * 64;
  __shared__ float in_s[16][64];
  __shared__ float red[18];
  __shared__ unsigned int lastv;
  float acc[16][2];
#pragma unroll
  for (int r = 0; r < 16; r++) { acc[r][0] = 0.f; acc[r][1] = 0.f; }
#pragma unroll
  for (int j = 0; j < 4; j++) {
    int ii = tid + j * 256;
    int r = ii >> 6, kk = ii & 63;
    int k = kbase + kk;
    float v = 0.f;
    if (k < SD) v = stoch_in[r * SD + k];
    else if (k < SD + A_DIM) v = a_eff[r * 8 + (k - SD)];
    in_s[r][kk] = v;
  }
  __syncthreads();
  if (kbase + 64 <= SD + A_DIM) {
    const float* wp = W + (size_t)kbase * HID + c0;
#pragma unroll 4
    for (int kk = 0; kk < 64; kk++) {
      f2v w = __builtin_nontemporal_load((const f2v*)wp);
      wp += HID;
#pragma unroll
      for (int r = 0; r < 16; r++) {
        acc[r][0] += in_s[r][kk] * w[0]; acc[r][1] += in_s[r][kk] * w[1];
      }
    }
  } else {
#pragma unroll 4
    for (int kk = 0; kk < 64; kk++) {
      int krow = kbase + kk; if (krow >= SD + A_DIM) krow = SD + A_DIM - 1;
      const f2v w = *(const f2v*)(W + (size_t)krow * HID + c0);
#pragma unroll
      for (int r = 0; r < 16; r++) {
        acc[r][0] += in_s[r][kk] * w[0]; acc[r][1] += in_s[r][kk] * w[1];
      }
    }
  }
#pragma unroll
  for (int r = 0; r < 16; r++)
    *(f2v*)(P + ((size_t)blockIdx.y * 16 + r) * HID + c0) = f2v{acc[r][0], acc[r][1]};
  // signal + last-block finish
  __threadfence();
  __syncthreads();
  if (tid == 0) lastv = atomicAdd(cnt, 1u);
  __syncthreads();
  if (lastv == 34u - 1u) {
    if (tid == 0) atomicExch(cnt, 0u);
    __threadfence();
    const int c = tid * 4;
    for (int r = 0; r < 16; r++) {
      f4v v = {0, 0, 0, 0};
      for (int ks = 0; ks < 17; ks++) {
        f4v pv = *(const f4v*)(P + ((size_t)ks * 16 + r) * HID + c);
        v[0] += pv[0]; v[1] += pv[1]; v[2] += pv[2]; v[3] += pv[3];
      }
      float lsum = (v[0] + v[1]) + (v[2] + v[3]);
      float m = block_sum(lsum, red, 4) * (1.0f / (float)HID);
      float d0 = v[0] - m, d1 = v[1] - m, d2 = v[2] - m, d3 = v[3] - m;
      float lv = (d0 * d0 + d1 * d1) + (d2 * d2 + d3 * d3);
      float var = block_sum(lv, red, 4) * (1.0f / (float)HID);
      float rs = 1.0f / sqrtf(var + 1e-3f);
      float dd[4] = {d0, d1, d2, d3};
      f4v o;
#pragma unroll
      for (int j = 0; j < 4; j++) {
        float y = dd[j] * rs * gv[c + j] + bv[c + j];
        o[j] = y / (1.0f + expf(-y));
      }
      *(f4v*)(xout + (size_t)r * HID + c) = o;
    }
  }
}

// ---- obs: per-block GRU-gate recompute (slice) + GEMM partials + last-block LN+silu -> h2.
// tile0 blocks also write deter to d_out and the ping-ponged next-step deter_in.
__global__ __launch_bounds__(256) void k_obsf(
    const float* __restrict__ Sg, const float* __restrict__ red_s, const float* __restrict__ red_q,
    const float* __restrict__ gg, const float* __restrict__ bg,
    const float* __restrict__ din_cur, float* __restrict__ din_next,
    const float* __restrict__ init_deter, const float* __restrict__ isf, int t,
    const float* __restrict__ W, const float* __restrict__ gv, const float* __restrict__ bv,
    float* __restrict__ out, float* __restrict__ h2,
    float* __restrict__ P, unsigned int* __restrict__ cnt) {
  const int tid = threadIdx.x;
  const int tile = blockIdx.x;       // 0..1 (col half)
  const int split = blockIdx.y;      // 0..31 (K slice of 128)
  const int c0 = tile * 512 + tid * 2;
  const int j0 = split * 128;
  __shared__ float dn_s[16][128];
  __shared__ float mvf[16][3];
  __shared__ float red[18];
  __shared__ unsigned int lastv;
  if (tid < 16) {
    int r = tid;
    float s = 0.f, q = 0.f;
    for (int k2 = 0; k2 < 12; k2++) { s += red_s[r * 12 + k2]; q += red_q[r * 12 + k2]; }
    float m = s * (1.0f / (float)(3 * DET));
    float var = q * (1.0f / (float)(3 * DET)) - m * m;
    mvf[r][0] = m; mvf[r][1] = 1.0f / sqrtf(var + 1e-3f);
    mvf[r][2] = (t + 1 < T_STEPS) ? isf[r * T_STEPS + t + 1] : 0.0f;
  }
  __syncthreads();
  for (int e = tid; e < 16 * 128; e += 256) {
    int r = e >> 7, jj = e & 127;
    int j = j0 + jj;
    float m = mvf[r][0], rs = mvf[r][1];
    const float* Sr = Sg + (size_t)r * (3 * DET);
    float lr = (Sr[j] - m) * rs * gg[j] + bg[j];
    float lc = (Sr[j + DET] - m) * rs * gg[j + DET] + bg[j + DET];
    float lu = (Sr[j + 2 * DET] - m) * rs * gg[j + 2 * DET] + bg[j + 2 * DET];
    float rr = 1.0f / (1.0f + expf(-lr));
    float cd = tanhf(rr * lc);
    float uu = 1.0f / (1.0f + expf(-(lu - 1.0f)));
    float dn = uu * cd + (1.0f - uu) * din_cur[r * DET + j];
    dn_s[r][jj] = dn;
    if (tile == 0) {
      out[(size_t)(r * T_STEPS + t) * OUT_C + 1024 + j] = dn;
      float ft = mvf[r][2];
      din_next[r * DET + j] = dn * (1.0f - ft) + init_deter[j] * ft;
    }
  }
  __syncthreads();
  float acc[16][2];
#pragma unroll
  for (int r = 0; r < 16; r++) { acc[r][0] = 0.f; acc[r][1] = 0.f; }
  for (int kb = 0; kb < 128; kb += 64) {
    const float* wp = W + (size_t)(j0 + kb) * HID + c0;
#pragma unroll 4
    for (int kk = 0; kk < 64; kk++) {
      f2v w = __builtin_nontemporal_load((const f2v*)wp);
      wp += HID;
#pragma unroll
      for (int r = 0; r < 16; r++) {
        float iv = dn_s[r][kb + kk];
        acc[r][0] += iv * w[0]; acc[r][1] += iv * w[1];
      }
    }
  }
#pragma unroll
  for (int r = 0; r < 16; r++)
    *(f2v*)(P + ((size_t)split * 16 + r) * HID + c0) = f2v{acc[r][0], acc[r][1]};
  // signal + last-block finish
  __threadfence();
  __syncthreads();
  if (tid == 0) lastv = atomicAdd(cnt, 1u);
  __syncthreads();
  if (lastv == 64u - 1u) {
    if (tid == 0) atomicExch(cnt, 0u);
    __threadfence();
    const int c = tid * 4;
    for (int r = 0; r < 16; r++) {
      f4v v = *(const f4v*)(out + (size_t)(r * T_STEPS + t) * OUT_C + 5120 + c);  // OE
      for (int ks = 0; ks < 32; ks++) {
        f4v pv = *(const f4v*)(P + ((size_t)ks * 16 + r) * HID + c);
        v[0] += pv[0]; v[1] += pv[1]; v[2] += pv[2]; v[3] += pv[3];
      }
      float lsum = (v[0] + v[1]) + (v[2] + v[3]);
      float m = block_sum(lsum, red, 4) * (1.0f / (float)HID);
      float d0 = v[0] - m, d1 = v[1] - m, d2 = v[2] - m, d3 = v[3] - m;
      float lv = (d0 * d0 + d1 * d1) + (d2 * d2 + d3 * d3);
      float var = block_sum(lv, red, 4) * (1.0f / (float)HID);
      float rs = 1.0f / sqrtf(var + 1e-3f);
      float dd[4] = {d0, d1, d2, d3};
      f4v o;
#pragma unroll
      for (int j = 0; j < 4; j++) {
        float y = dd[j] * rs * gv[c + j] + bv[c + j];
        o[j] = y / (1.0f + expf(-y));
      }
      *(f4v*)(h2 + (size_t)r * HID + c) = o;
    }
  }
}

// ---- post: GEMM partials (32 blocks) + last-block sample + next-step stoch/a blend ----
__global__ __launch_bounds__(256) void k_postf(
    const float* __restrict__ h2, const float* __restrict__ W,
    const float* __restrict__ bb, const float* __restrict__ gum, long gs,
    float* __restrict__ out, int t,
    const float* __restrict__ isf, const float* __restrict__ pa,
    float* __restrict__ stoch_in, float* __restrict__ a_eff,
    const float* __restrict__ init_stoch,
    float* __restrict__ P, unsigned int* __restrict__ cnt) {
  const int tid = threadIdx.x;
  const int c0 = blockIdx.x * 512 + tid * 2;
  const int kbase = (int)blockIdx.y * 64;
  __shared__ float in_s[16][64];
  __shared__ unsigned int lastv;
  float acc[16][2];
#pragma unroll
  for (int r = 0; r < 16; r++) { acc[r][0] = 0.f; acc[r][1] = 0.f; }
#pragma unroll
  for (int j = 0; j < 4; j++) {
    int ii = tid + j * 256;
    int r = ii >> 6, kk = ii & 63;
    in_s[r][kk] = h2[r * HID + kbase + kk];
  }
  __syncthreads();
  {
    const float* wp = W + (size_t)kbase * SD + c0;
#pragma unroll 4
    for (int kk = 0; kk < 64; kk++) {
      f2v w = __builtin_nontemporal_load((const f2v*)wp);
      wp += SD;
#pragma unroll
      for (int r = 0; r < 16; r++) {
        acc[r][0] += in_s[r][kk] * w[0]; acc[r][1] += in_s[r][kk] * w[1];
      }
    }
  }
#pragma unroll
  for (int r = 0; r < 16; r++)
    *(f2v*)(P + ((size_t)blockIdx.y * 16 + r) * SD + c0) = f2v{acc[r][0], acc[r][1]};
  // signal + last-block finish
  __threadfence();
  __syncthreads();
  if (tid == 0) lastv = atomicAdd(cnt, 1u);
  __syncthreads();
  if (lastv == 32u - 1u) {
    if (tid == 0) atomicExch(cnt, 0u);
    __threadfence();
    const int d = tid & 31;
    for (int it = 0; it < 64; it++) {
      int gi = it * 8 + (tid >> 5);   // 512 (row,group) pairs, 8 per pass
      int r = gi >> 5, grp = gi & 31;
      int c = grp * 32 + d;
      float a = bb[c];
      for (int ks = 0; ks < 16; ks++) a += P[((size_t)ks * 16 + r) * SD + c];
      float mx = a;
#pragma unroll
      for (int m = 16; m >= 1; m >>= 1) mx = fmaxf(mx, __shfl_xor(mx, m, 32));
      float e = expf(a - mx);
      float se = e;
#pragma unroll
      for (int m = 16; m >= 1; m >>= 1) se += __shfl_xor(se, m, 32);
      float p = 0.99f * (e / se) + 3.125e-4f;
      float y = logf(p) + gum[(long)r * gs + c];
      float by = y; int bi = d;
#pragma unroll
      for (int m = 16; m >= 1; m >>= 1) {
        float oy = __shfl_xor(by, m, 32);
        int oi = __shfl_xor(bi, m, 32);
        if (oy > by || (oy == by && oi < bi)) { by = oy; bi = oi; }
      }
      float oh = (d == bi) ? 1.0f : 0.0f;
      float outv = (oh + p) - p;
      float* ob = out + (size_t)(r * T_STEPS + t) * OUT_C;
      ob[c] = outv;
      ob[5120 + c] = a;
      float fn = (t + 1 < T_STEPS) ? isf[r * T_STEPS + t + 1] : 0.0f;
      stoch_in[r * SD + c] = outv * (1.0f - fn) + init_stoch[r * SD + c] * fn;
      if (c < A_DIM) {
        float av = (t + 1 < T_STEPS) ? pa[(r * T_STEPS + t + 1) * A_DIM + c] : 0.0f;
        av = av * (1.0f / fmaxf(fabsf(av), 1.0f));
        a_eff[r * 8 + c] = av * (1.0f - fn);
      }
    }
  }
}

// ---------------- host ----------------
static inline GemmArgs mkargs(const float* A0, long sA0, int cA0,
                              const float* A1, long sA1,
                              const float* W, int N, int Ktot, int KS, int nsplit, float* P) {
  GemmArgs g; g.A0 = A0; g.sA0 = sA0; g.cA0 = cA0; g.A1 = A1; g.sA1 = sA1;
  g.W = W; g.N = N; g.Ktot = Ktot; g.KS = KS; g.nsplit = nsplit; g.P = P;
  return g;
}

extern "C" void kernel_launch(void* const* d_in, const int* in_sizes, int n_in,
                              void* d_out, int out_size, void* d_ws, size_t ws_size,
                              hipStream_t stream) {
  const float* embed  = (const float*)d_in[0];
  const float* pa     = (const float*)d_in[1];
  const float* isf    = (const float*)d_in[2];
  const float* gprior = (const float*)d_in[3];
  const float* gpost  = (const float*)d_in[4];
  const float* w_init = (const float*)d_in[5];
  const float* W1  = (const float*)d_in[6];
  const float* g1  = (const float*)d_in[7];
  const float* b1  = (const float*)d_in[8];
  const float* Wg  = (const float*)d_in[9];
  const float* gg  = (const float*)d_in[10];
  const float* bg  = (const float*)d_in[11];
  const float* W2a = (const float*)d_in[12];
  const float* g2  = (const float*)d_in[13];
  const float* b2  = (const float*)d_in[14];
  const float* W2b = (const float*)d_in[15];
  const float* bb2 = (const float*)d_in[16];
  const float* Wo  = (const float*)d_in[17];
  const float* go  = (const float*)d_in[18];
  const float* bo  = (const float*)d_in[19];
  const float* Wob = (const float*)d_in[20];
  const float* bbo = (const float*)d_in[21];
  float* out = (float*)d_out;
  float* ws  = (float*)d_ws;

  // workspace (floats)
  float* Pg    = ws;                    // 20*16*12288 = 3,932,160 (aliased: h_all deferred)
  float* h_all = Pg;                    // 1024*1024
  float* Sg    = Pg + 3932160;          // 196,608
  float* red_s = Sg + 196608;           // 192
  float* red_q = red_s + 192;           // 192
  unsigned int* cnts = (unsigned int*)(red_s + 384);  // 3 counters (pad region)
  float* Pimg1 = red_s + 512;           // 17*16*1024 = 278,528
  float* Pb    = Pimg1 + 278528;        // 32*16*1024 = 524,288
  float* Ps1   = Pb + 524288;           // 16*16*1024 = 262,144
  float* st_   = Ps1 + 262144;
  float* init_stoch = st_;              // 16,384
  float* init_deter = st_ + 16384;      // 4,096
  float* stoch_in   = st_ + 20480;      // 16,384
  float* din0       = st_ + 36864;      // 65,536
  float* din1       = st_ + 102400;     // 65,536
  float* a_eff      = st_ + 167936;     // 128
  float* x          = st_ + 168064;     // 16,384
  float* h2         = st_ + 184448;     // 16,384

  hipMemsetAsync(cnts, 0, 64, stream);  // ws is 0xAA-poisoned; counters must start 0

  // ---- OE precompute: e @ Wo[0:E] -> out post-logit slots (consumed in-loop, overwritten)
  k_mm<<<dim3(16, 16), 256, 0, stream>>>(embed, E_DIM, Wo, E_DIM, out + 5120, OUT_C, nullptr);

  // ---- init: init_deter = tanh(w_init); init_stoch = st_mode(prior_logits(init_deter))
  k_tanh<<<4, 1024, 0, stream>>>(w_init, init_deter);
  k_gemm<true><<<dim3(2, 32), 256, 0, stream>>>(
      mkargs(init_deter, 0, DET, nullptr, 0, W2a, HID, DET, 128, 32, Pb));
  k_fin<<<16, 1024, 0, stream>>>(Pb, 32, g2, b2, x);
  k_gemm<true><<<dim3(2, 16), 256, 0, stream>>>(
      mkargs(x, HID, HID, nullptr, 0, W2b, SD, HID, 64, 16, Ps1));
  k_samp_init<<<16, 1024, 0, stream>>>(Ps1, 16, bb2, init_stoch);

  // ---- t=0 prep (f[:,0]==1 -> all init) ----
  k_prep<<<16, 256, 0, stream>>>(isf, pa, 0, init_stoch, init_deter, 0,
                                 init_stoch, init_deter, stoch_in, din0, a_eff);

  const float* Wo2 = Wo + (size_t)E_DIM * HID;
  for (int t = 0; t < T_STEPS; t++) {
    float* din_cur  = (t & 1) ? din1 : din0;
    float* din_next = (t & 1) ? din0 : din1;
    // 1) img1 fused: partials + LN+silu -> x
    k_img1f<<<dim3(2, 17), 256, 0, stream>>>(stoch_in, a_eff, W1, g1, b1, Pimg1, x, cnts + 0);
    // 2) GRU GEMM: concat(x, deter_in)[5120] @ Wg -> 12288 partials (Wg cacheable)
    k_gemm<false><<<dim3(24, 20), 256, 0, stream>>>(
        mkargs(x, HID, HID, din_cur, DET, Wg, 3 * DET, HID + DET, 256, 20, Pg));
    // 3) reduce partials -> Sg + per-chunk (sum, sumsq)
    k_red<<<dim3(12, 16), 256, 0, stream>>>(Pg, 20, Sg, red_s, red_q);
    // 4) obs fused: gate recompute per slice + GEMM + LN+silu -> h2 (tile0 writes deter)
    k_obsf<<<dim3(2, 32), 256, 0, stream>>>(Sg, red_s, red_q, gg, bg, din_cur, din_next,
                                            init_deter, isf, t, Wo2, go, bo, out, h2,
                                            Pb, cnts + 1);
    // 5) post fused: GEMM + sample + next-step blends
    k_postf<<<dim3(2, 16), 256, 0, stream>>>(h2, Wob, bbo,
                                             gpost + (size_t)t * SD, (long)T_STEPS * SD,
                                             out, t, isf, pa, stoch_in, a_eff, init_stoch,
                                             Ps1, cnts + 2);
  }

  // ---- deferred prior branch (batched over all (b,t)) ----
  k_mm<<<dim3(16, 16), 256, 0, stream>>>(out + 1024, OUT_C, W2a, DET, h_all, HID, nullptr);
  k_ln_rows<<<1024, 256, 0, stream>>>(h_all, g2, b2);
  k_mm<<<dim3(16, 16), 256, 0, stream>>>(h_all, HID, W2b, HID, out + 7168, OUT_C, bb2);
  k_samp_prior<<<1024, 1024, 0, stream>>>(out, gprior);
}

// Round 8
// 12043.215 us; speedup vs baseline: 1.9586x; 1.9586x over previous
//
#include <hip/hip_runtime.h>
#include <cmath>

// RSSM scan: B=16, T=64, A=6, E=12288, DET=4096, HID=1024, S=32, D=32
// fp32 throughout (argmax stability). Deterministic fixed-order reductions.
// 8 launches/step: img1G, img1F, gruG(40-split), red, obsG(gate fused), obsF, postG, samp.

#define B 16
#define T_STEPS 64
#define A_DIM 6
#define E_DIM 12288
#define DET 4096
#define HID 1024
#define SD 1024
#define OUT_C 8192
#define OUT_RSTRIDE (T_STEPS * OUT_C)

typedef float f2v __attribute__((ext_vector_type(2)));
typedef float f4v __attribute__((ext_vector_type(4)));

// ---------------- block reduce (deterministic) ----------------
__device__ __forceinline__ float block_sum(float v, float* red, int nw) {
#pragma unroll
  for (int m = 32; m >= 1; m >>= 1) v += __shfl_xor(v, m, 64);
  int wid = threadIdx.x >> 6;
  if ((threadIdx.x & 63) == 0) red[wid] = v;
  __syncthreads();
  if (wid == 0) {
    float s = ((int)threadIdx.x < nw) ? red[threadIdx.x] : 0.0f;
#pragma unroll
    for (int m = 8; m >= 1; m >>= 1) s += __shfl_xor(s, m, 16);
    if (threadIdx.x == 0) red[0] = s;
  }
  __syncthreads();
  float out = red[0];
  __syncthreads();
  return out;
}

__global__ __launch_bounds__(1024) void k_tanh(const float* __restrict__ w, float* __restrict__ o) {
  int i = blockIdx.x * 1024 + threadIdx.x;
  if (i < DET) o[i] = tanhf(w[i]);
}

// ---------------- prep (t=0 only) ----------------
__global__ __launch_bounds__(256) void k_prep(
    const float* __restrict__ isf, const float* __restrict__ pa, int t,
    const float* __restrict__ stoch_prev,
    const float* __restrict__ deter_prev, long deter_prev_stride,
    const float* __restrict__ init_stoch, const float* __restrict__ init_deter_row,
    float* __restrict__ stoch_in, float* __restrict__ deter_in, float* __restrict__ a_eff) {
  int r = blockIdx.x;
  float f = isf[r * T_STEPS + t];
  float omf = 1.0f - f;
  for (int c = threadIdx.x; c < SD; c += 256)
    stoch_in[r * SD + c] = stoch_prev[r * SD + c] * omf + init_stoch[r * SD + c] * f;
  for (int c = threadIdx.x; c < DET; c += 256)
    deter_in[r * DET + c] = deter_prev[(long)r * deter_prev_stride + c] * omf + init_deter_row[c] * f;
  if ((int)threadIdx.x < A_DIM) {
    float a = pa[(r * T_STEPS + t) * A_DIM + threadIdx.x];
    a = a * (1.0f / fmaxf(fabsf(a), 1.0f));
    a_eff[r * 8 + threadIdx.x] = a * omf;
  }
}

// ---------------- K-split GEMM: P[split][16][N] partials (round-3 body) ----------------
struct GemmArgs {
  const float* A0; long sA0; int cA0;
  const float* A1; long sA1;
  const float* W; int N; int Ktot; int KS; int nsplit;
  float* P;
};

template <bool NT>
__global__ __launch_bounds__(256) void k_gemm(GemmArgs g) {
  if ((int)blockIdx.y >= g.nsplit) return;
  const int tid = threadIdx.x;
  const int c0 = blockIdx.x * 512 + tid * 2;
  const int k0 = (int)blockIdx.y * g.KS;
  __shared__ float in_s[16][64];
  float acc[16][2];
#pragma unroll
  for (int r = 0; r < 16; r++) { acc[r][0] = 0.f; acc[r][1] = 0.f; }
  for (int kb = 0; kb < g.KS; kb += 64) {
    const int kbase = k0 + kb;
#pragma unroll
    for (int j = 0; j < 4; j++) {
      int ii = tid + j * 256;
      int r = ii >> 6, kk = ii & 63;
      int k = kbase + kk;
      float v = 0.f;
      if (k < g.cA0) v = g.A0[(long)r * g.sA0 + k];
      else if (k < g.Ktot) v = g.A1[(long)r * g.sA1 + (k - g.cA0)];
      in_s[r][kk] = v;
    }
    __syncthreads();
    if (kbase + 64 <= g.Ktot) {
      const float* wp = g.W + (size_t)kbase * g.N + c0;
#pragma unroll 4
      for (int kk = 0; kk < 64; kk++) {
        f2v w = NT ? __builtin_nontemporal_load((const f2v*)wp) : *(const f2v*)wp;
        wp += g.N;
#pragma unroll
        for (int r = 0; r < 16; r++) {
          acc[r][0] += in_s[r][kk] * w[0]; acc[r][1] += in_s[r][kk] * w[1];
        }
      }
    } else {  // K tail (img1: Ktot=1030)
#pragma unroll 4
      for (int kk = 0; kk < 64; kk++) {
        int krow = kbase + kk; if (krow >= g.Ktot) krow = g.Ktot - 1;
        const f2v w = *(const f2v*)(g.W + (size_t)krow * g.N + c0);
#pragma unroll
        for (int r = 0; r < 16; r++) {
          acc[r][0] += in_s[r][kk] * w[0]; acc[r][1] += in_s[r][kk] * w[1];
        }
      }
    }
    __syncthreads();
  }
#pragma unroll
  for (int r = 0; r < 16; r++)
    *(f2v*)(g.P + ((size_t)blockIdx.y * 16 + r) * g.N + c0) = f2v{acc[r][0], acc[r][1]};
}

// ---------------- finish: (optional add) + sum partials + LN + silu ----------------
__global__ __launch_bounds__(1024) void k_fin(
    const float* __restrict__ P, int nP,
    const float* __restrict__ add, long ads,
    const float* __restrict__ gv, const float* __restrict__ bv,
    float* __restrict__ o) {
  int r = blockIdx.x, c = threadIdx.x;
  __shared__ float red[18];
  float v = add ? add[(size_t)r * ads + c] : 0.0f;
  for (int ks = 0; ks < nP; ks++) v += P[((size_t)ks * 16 + r) * HID + c];
  float m = block_sum(v, red, 16) * (1.0f / (float)HID);
  float d = v - m;
  float var = block_sum(d * d, red, 16) * (1.0f / (float)HID);
  float rs = 1.0f / sqrtf(var + 1e-3f);
  float y = d * rs * gv[c] + bv[c];
  float s = 1.0f / (1.0f + expf(-y));
  o[r * HID + c] = y * s;
}

// ---------------- init sample (mode) ----------------
__global__ __launch_bounds__(1024) void k_samp_init(
    const float* __restrict__ P, int nP, const float* __restrict__ bb,
    float* __restrict__ st) {
  int r = blockIdx.x, c = threadIdx.x;
  float acc = bb[c];
  for (int ks = 0; ks < nP; ks++) acc += P[((size_t)ks * 16 + r) * SD + c];
  int d = c & 31;
  float mx = acc;
#pragma unroll
  for (int m = 16; m >= 1; m >>= 1) mx = fmaxf(mx, __shfl_xor(mx, m, 32));
  float e = expf(acc - mx);
  float se = e;
#pragma unroll
  for (int m = 16; m >= 1; m >>= 1) se += __shfl_xor(se, m, 32);
  float p = 0.99f * (e / se) + 3.125e-4f;
  float by = p; int bi = d;
#pragma unroll
  for (int m = 16; m >= 1; m >>= 1) {
    float oy = __shfl_xor(by, m, 32);
    int oi = __shfl_xor(bi, m, 32);
    if (oy > by || (oy == by && oi < bi)) { by = oy; bi = oi; }
  }
  float oh = (d == bi) ? 1.0f : 0.0f;
  st[r * SD + c] = (oh + p) - p;
}

// ---------------- tiled GEMM: out[M x 1024] = A[M x K] @ Bw[K x 1024] (+bias) ----------
__global__ __launch_bounds__(256) void k_mm(const float* __restrict__ A, long lda,
                                            const float* __restrict__ Bw, int K,
                                            float* __restrict__ out, long ldo,
                                            const float* __restrict__ bias) {
  __shared__ float As[32][68];
  __shared__ float Bs[32][68];
  const int tid = threadIdx.x;
  const int tx = tid & 15, ty = tid >> 4;
  const int row0 = blockIdx.y * 64, col0 = blockIdx.x * 64;
  const int ar = tid >> 2, ak = (tid & 3) * 8;
  const int bk = tid >> 4, bc = (tid & 15) * 4;
  float acc[4][4] = {};
  const float* ap = A + (size_t)(row0 + ar) * lda + ak;
  const float* bp = Bw + (size_t)bk * HID + col0 + bc;
  for (int k0 = 0; k0 < K; k0 += 32) {
    float4 a0 = *(const float4*)(ap + k0);
    float4 a1 = *(const float4*)(ap + k0 + 4);
    float4 b0 = *(const float4*)(bp + (size_t)k0 * HID);
    float4 b1 = *(const float4*)(bp + (size_t)(k0 + 16) * HID);
    __syncthreads();
    As[ak + 0][ar] = a0.x; As[ak + 1][ar] = a0.y; As[ak + 2][ar] = a0.z; As[ak + 3][ar] = a0.w;
    As[ak + 4][ar] = a1.x; As[ak + 5][ar] = a1.y; As[ak + 6][ar] = a1.z; As[ak + 7][ar] = a1.w;
    *(float4*)&Bs[bk][bc] = b0;
    *(float4*)&Bs[bk + 16][bc] = b1;
    __syncthreads();
#pragma unroll
    for (int kk = 0; kk < 32; kk++) {
      float4 av = *(const float4*)&As[kk][ty * 4];
      float4 bv = *(const float4*)&Bs[kk][tx * 4];
      acc[0][0] += av.x * bv.x; acc[0][1] += av.x * bv.y; acc[0][2] += av.x * bv.z; acc[0][3] += av.x * bv.w;
      acc[1][0] += av.y * bv.x; acc[1][1] += av.y * bv.y; acc[1][2] += av.y * bv.z; acc[1][3] += av.y * bv.w;
      acc[2][0] += av.z * bv.x; acc[2][1] += av.z * bv.y; acc[2][2] += av.z * bv.z; acc[2][3] += av.z * bv.w;
      acc[3][0] += av.w * bv.x; acc[3][1] += av.w * bv.y; acc[3][2] += av.w * bv.z; acc[3][3] += av.w * bv.w;
    }
  }
#pragma unroll
  for (int i = 0; i < 4; i++) {
    float4 o;
    int col = col0 + tx * 4;
    o.x = acc[i][0] + (bias ? bias[col + 0] : 0.f);
    o.y = acc[i][1] + (bias ? bias[col + 1] : 0.f);
    o.z = acc[i][2] + (bias ? bias[col + 2] : 0.f);
    o.w = acc[i][3] + (bias ? bias[col + 3] : 0.f);
    *(float4*)(out + (size_t)(row0 + ty * 4 + i) * ldo + col) = o;
  }
}

// ---------------- deferred: per-row LN + silu in place ----------------
__global__ __launch_bounds__(256) void k_ln_rows(float* __restrict__ h,
                                                 const float* __restrict__ gv,
                                                 const float* __restrict__ bv) {
  int row = blockIdx.x, c0 = threadIdx.x * 4;
  __shared__ float red[18];
  float4 v = *(const float4*)(h + (size_t)row * HID + c0);
  float lsum = (v.x + v.y) + (v.z + v.w);
  float m = block_sum(lsum, red, 4) * (1.0f / (float)HID);
  float dx = v.x - m, dy = v.y - m, dz = v.z - m, dw = v.w - m;
  float lv = (dx * dx + dy * dy) + (dz * dz + dw * dw);
  float var = block_sum(lv, red, 4) * (1.0f / (float)HID);
  float rs = 1.0f / sqrtf(var + 1e-3f);
  float4 o;
  float y0 = dx * rs * gv[c0] + bv[c0];         o.x = y0 / (1.0f + expf(-y0));
  float y1 = dy * rs * gv[c0 + 1] + bv[c0 + 1]; o.y = y1 / (1.0f + expf(-y1));
  float y2 = dz * rs * gv[c0 + 2] + bv[c0 + 2]; o.z = y2 / (1.0f + expf(-y2));
  float y3 = dw * rs * gv[c0 + 3] + bv[c0 + 3]; o.w = y3 / (1.0f + expf(-y3));
  *(float4*)(h + (size_t)row * HID + c0) = o;
}

// ---------------- deferred: batched prior sample (logits in out+7168) ----------------
__global__ __launch_bounds__(1024) void k_samp_prior(float* __restrict__ out,
                                                     const float* __restrict__ gum) {
  int m = blockIdx.x, c = threadIdx.x;
  float lp = out[(size_t)m * OUT_C + 7168 + c];
  int d = c & 31;
  float mx = lp;
#pragma unroll
  for (int mm = 16; mm >= 1; mm >>= 1) mx = fmaxf(mx, __shfl_xor(mx, mm, 32));
  float e = expf(lp - mx);
  float se = e;
#pragma unroll
  for (int mm = 16; mm >= 1; mm >>= 1) se += __shfl_xor(se, mm, 32);
  float p = 0.99f * (e / se) + 3.125e-4f;
  float y = logf(p) + gum[(size_t)m * SD + c];
  float by = y; int bi = d;
#pragma unroll
  for (int mm = 16; mm >= 1; mm >>= 1) {
    float oy = __shfl_xor(by, mm, 32);
    int oi = __shfl_xor(bi, mm, 32);
    if (oy > by || (oy == by && oi < bi)) { by = oy; bi = oi; }
  }
  float oh = (d == bi) ? 1.0f : 0.0f;
  out[(size_t)m * OUT_C + 6144 + c] = (oh + p) - p;
}

// ---------------- GRU stage-1 reduce: sum splits + (sum, sumsq) per chunk ----------
__global__ __launch_bounds__(256) void k_red(const float* __restrict__ P, int nP,
                                             float* __restrict__ S,
                                             float* __restrict__ red_s, float* __restrict__ red_q) {
  int chunk = blockIdx.x, r = blockIdx.y;
  int c = chunk * 1024 + threadIdx.x * 4;
  float4 s = {0, 0, 0, 0};
  for (int ks = 0; ks < nP; ks++) {
    float4 v = *(const float4*)(P + ((size_t)ks * 16 + r) * (3 * DET) + c);
    s.x += v.x; s.y += v.y; s.z += v.z; s.w += v.w;
  }
  *(float4*)(S + (size_t)r * (3 * DET) + c) = s;
  float sx = (s.x + s.y) + (s.z + s.w);
  float sq = (s.x * s.x + s.y * s.y) + (s.z * s.z + s.w * s.w);
  __shared__ float rbuf[8];
#pragma unroll
  for (int m = 32; m >= 1; m >>= 1) { sx += __shfl_xor(sx, m, 64); sq += __shfl_xor(sq, m, 64); }
  int wid = threadIdx.x >> 6;
  if ((threadIdx.x & 63) == 0) { rbuf[wid] = sx; rbuf[4 + wid] = sq; }
  __syncthreads();
  if (threadIdx.x == 0) {
    red_s[r * 12 + chunk] = (rbuf[0] + rbuf[1]) + (rbuf[2] + rbuf[3]);
    red_q[r * 12 + chunk] = (rbuf[4] + rbuf[5]) + (rbuf[6] + rbuf[7]);
  }
}

// ---- obs GEMM with fused GRU-gate recompute (per 128-col K-slice; no fence) ----
// tile0 blocks also write deter to d_out and the ping-ponged next-step deter_in.
__global__ __launch_bounds__(256) void k_obsg(
    const float* __restrict__ Sg, const float* __restrict__ red_s, const float* __restrict__ red_q,
    const float* __restrict__ gg, const float* __restrict__ bg,
    const float* __restrict__ din_cur, float* __restrict__ din_next,
    const float* __restrict__ init_deter, const float* __restrict__ isf, int t,
    const float* __restrict__ W,
    float* __restrict__ out, float* __restrict__ P) {
  const int tid = threadIdx.x;
  const int tile = blockIdx.x;       // 0..1 (col half)
  const int split = blockIdx.y;      // 0..31 (K slice of 128)
  const int c0 = tile * 512 + tid * 2;
  const int j0 = split * 128;
  __shared__ float dn_s[16][128];
  __shared__ float mvf[16][3];
  if (tid < 16) {
    int r = tid;
    float s = 0.f, q = 0.f;
    for (int k2 = 0; k2 < 12; k2++) { s += red_s[r * 12 + k2]; q += red_q[r * 12 + k2]; }
    float m = s * (1.0f / (float)(3 * DET));
    float var = q * (1.0f / (float)(3 * DET)) - m * m;
    mvf[r][0] = m; mvf[r][1] = 1.0f / sqrtf(var + 1e-3f);
    mvf[r][2] = (t + 1 < T_STEPS) ? isf[r * T_STEPS + t + 1] : 0.0f;
  }
  __syncthreads();
  for (int e = tid; e < 16 * 128; e += 256) {
    int r = e >> 7, jj = e & 127;
    int j = j0 + jj;
    float m = mvf[r][0], rs = mvf[r][1];
    const float* Sr = Sg + (size_t)r * (3 * DET);
    float lr = (Sr[j] - m) * rs * gg[j] + bg[j];
    float lc = (Sr[j + DET] - m) * rs * gg[j + DET] + bg[j + DET];
    float lu = (Sr[j + 2 * DET] - m) * rs * gg[j + 2 * DET] + bg[j + 2 * DET];
    float rr = 1.0f / (1.0f + expf(-lr));
    float cd = tanhf(rr * lc);
    float uu = 1.0f / (1.0f + expf(-(lu - 1.0f)));
    float dn = uu * cd + (1.0f - uu) * din_cur[r * DET + j];
    dn_s[r][jj] = dn;
    if (tile == 0) {
      out[(size_t)(r * T_STEPS + t) * OUT_C + 1024 + j] = dn;
      float ft = mvf[r][2];
      din_next[r * DET + j] = dn * (1.0f - ft) + init_deter[j] * ft;
    }
  }
  __syncthreads();
  float acc[16][2];
#pragma unroll
  for (int r = 0; r < 16; r++) { acc[r][0] = 0.f; acc[r][1] = 0.f; }
  for (int kb = 0; kb < 128; kb += 64) {
    const float* wp = W + (size_t)(j0 + kb) * HID + c0;
#pragma unroll 4
    for (int kk = 0; kk < 64; kk++) {
      f2v w = __builtin_nontemporal_load((const f2v*)wp);
      wp += HID;
#pragma unroll
      for (int r = 0; r < 16; r++) {
        float iv = dn_s[r][kb + kk];
        acc[r][0] += iv * w[0]; acc[r][1] += iv * w[1];
      }
    }
  }
#pragma unroll
  for (int r = 0; r < 16; r++)
    *(f2v*)(P + ((size_t)split * 16 + r) * HID + c0) = f2v{acc[r][0], acc[r][1]};
}

// ---------------- post sample + next-step stoch/a blend ----------------
__global__ __launch_bounds__(1024) void k_samp(
    const float* __restrict__ P, int nP, const float* __restrict__ bb,
    const float* __restrict__ gum, long gs,
    float* __restrict__ st, long ss, float* __restrict__ lg, long ls,
    const float* __restrict__ isf, const float* __restrict__ pa, int t,
    float* __restrict__ stoch_in, float* __restrict__ a_eff,
    const float* __restrict__ init_stoch) {
  int r = blockIdx.x, c = threadIdx.x;
  float acc = bb[c];
  for (int ks = 0; ks < nP; ks++) acc += P[((size_t)ks * 16 + r) * SD + c];
  int d = c & 31;
  float mx = acc;
#pragma unroll
  for (int m = 16; m >= 1; m >>= 1) mx = fmaxf(mx, __shfl_xor(mx, m, 32));
  float e = expf(acc - mx);
  float se = e;
#pragma unroll
  for (int m = 16; m >= 1; m >>= 1) se += __shfl_xor(se, m, 32);
  float p = 0.99f * (e / se) + 3.125e-4f;
  float y = logf(p) + gum[(long)r * gs + c];
  float by = y; int bi = d;
#pragma unroll
  for (int m = 16; m >= 1; m >>= 1) {
    float oy = __shfl_xor(by, m, 32);
    int oi = __shfl_xor(bi, m, 32);
    if (oy > by || (oy == by && oi < bi)) { by = oy; bi = oi; }
  }
  float oh = (d == bi) ? 1.0f : 0.0f;
  float outv = (oh + p) - p;
  st[(long)r * ss + c] = outv;
  lg[(long)r * ls + c] = acc;
  float fn = (t + 1 < T_STEPS) ? isf[r * T_STEPS + t + 1] : 0.0f;
  stoch_in[r * SD + c] = outv * (1.0f - fn) + init_stoch[r * SD + c] * fn;
  if (c < A_DIM) {
    float a = (t + 1 < T_STEPS) ? pa[(r * T_STEPS + t + 1) * A_DIM + c] : 0.0f;
    a = a * (1.0f / fmaxf(fabsf(a), 1.0f));
    a_eff[r * 8 + c] = a * (1.0f - fn);
  }
}

// ---------------- host ----------------
static inline GemmArgs mkargs(const float* A0, long sA0, int cA0,
                              const float* A1, long sA1,
                              const float* W, int N, int Ktot, int KS, int nsplit, float* P) {
  GemmArgs g; g.A0 = A0; g.sA0 = sA0; g.cA0 = cA0; g.A1 = A1; g.sA1 = sA1;
  g.W = W; g.N = N; g.Ktot = Ktot; g.KS = KS; g.nsplit = nsplit; g.P = P;
  return g;
}

extern "C" void kernel_launch(void* const* d_in, const int* in_sizes, int n_in,
                              void* d_out, int out_size, void* d_ws, size_t ws_size,
                              hipStream_t stream) {
  const float* embed  = (const float*)d_in[0];
  const float* pa     = (const float*)d_in[1];
  const float* isf    = (const float*)d_in[2];
  const float* gprior = (const float*)d_in[3];
  const float* gpost  = (const float*)d_in[4];
  const float* w_init = (const float*)d_in[5];
  const float* W1  = (const float*)d_in[6];
  const float* g1  = (const float*)d_in[7];
  const float* b1  = (const float*)d_in[8];
  const float* Wg  = (const float*)d_in[9];
  const float* gg  = (const float*)d_in[10];
  const float* bg  = (const float*)d_in[11];
  const float* W2a = (const float*)d_in[12];
  const float* g2  = (const float*)d_in[13];
  const float* b2  = (const float*)d_in[14];
  const float* W2b = (const float*)d_in[15];
  const float* bb2 = (const float*)d_in[16];
  const float* Wo  = (const float*)d_in[17];
  const float* go  = (const float*)d_in[18];
  const float* bo  = (const float*)d_in[19];
  const float* Wob = (const float*)d_in[20];
  const float* bbo = (const float*)d_in[21];
  float* out = (float*)d_out;
  float* ws  = (float*)d_ws;

  // GRU split count chosen from scratch budget (deterministic given fixed ws_size)
  const size_t STATE_FLOATS = 196608 + 512 + 200832;  // Sg + red/pad + states
  int NSPLIT = 40, KSG = 128;
  if (ws_size < ((size_t)40 * 16 * 12288 + STATE_FLOATS) * 4) { NSPLIT = 20; KSG = 256; }
  const size_t ASZ = (size_t)NSPLIT * 16 * 12288;

  // workspace (floats): one arena, partial buffers aliased (strictly sequential lifetimes)
  float* arena = ws;
  float* Pg    = arena;                 // NSPLIT*16*12288
  float* h_all = arena;                 // 1024*1024 (deferred, after loop)
  float* Pimg1 = arena;                 // 17*16*1024 = 278,528 (dead before gruG writes)
  float* Pb    = arena + ASZ - 786432;  // 32*16*1024 = 524,288
  float* Ps1   = arena + ASZ - 262144;  // 16*16*1024 = 262,144
  float* Sg    = arena + ASZ;           // 196,608
  float* red_s = Sg + 196608;           // 192
  float* red_q = red_s + 192;           // 192 (+pad)
  float* st_   = red_s + 512;
  float* init_stoch = st_;              // 16,384
  float* init_deter = st_ + 16384;      // 4,096
  float* stoch_in   = st_ + 20480;      // 16,384
  float* din0       = st_ + 36864;      // 65,536
  float* din1       = st_ + 102400;     // 65,536
  float* a_eff      = st_ + 167936;     // 128
  float* x          = st_ + 168064;     // 16,384
  float* h2         = st_ + 184448;     // 16,384

  // ---- OE precompute: e @ Wo[0:E] -> out post-logit slots (consumed in-loop, overwritten)
  k_mm<<<dim3(16, 16), 256, 0, stream>>>(embed, E_DIM, Wo, E_DIM, out + 5120, OUT_C, nullptr);

  // ---- init: init_deter = tanh(w_init); init_stoch = st_mode(prior_logits(init_deter))
  k_tanh<<<4, 1024, 0, stream>>>(w_init, init_deter);
  k_gemm<true><<<dim3(2, 32), 256, 0, stream>>>(
      mkargs(init_deter, 0, DET, nullptr, 0, W2a, HID, DET, 128, 32, Pb));
  k_fin<<<16, 1024, 0, stream>>>(Pb, 32, nullptr, 0, g2, b2, x);
  k_gemm<true><<<dim3(2, 16), 256, 0, stream>>>(
      mkargs(x, HID, HID, nullptr, 0, W2b, SD, HID, 64, 16, Ps1));
  k_samp_init<<<16, 1024, 0, stream>>>(Ps1, 16, bb2, init_stoch);

  // ---- t=0 prep (f[:,0]==1 -> all init) ----
  k_prep<<<16, 256, 0, stream>>>(isf, pa, 0, init_stoch, init_deter, 0,
                                 init_stoch, init_deter, stoch_in, din0, a_eff);

  const float* Wo2 = Wo + (size_t)E_DIM * HID;
  for (int t = 0; t < T_STEPS; t++) {
    float* din_cur  = (t & 1) ? din1 : din0;
    float* din_next = (t & 1) ? din0 : din1;
    // 1) img1 GEMM: concat(stoch,a)[1030] @ W1 -> 1024 partials
    k_gemm<true><<<dim3(2, 17), 256, 0, stream>>>(
        mkargs(stoch_in, SD, SD, a_eff, 8, W1, HID, SD + A_DIM, 64, 17, Pimg1));
    // 2) img1 finish -> x
    k_fin<<<16, 1024, 0, stream>>>(Pimg1, 17, nullptr, 0, g1, b1, x);
    // 3) GRU GEMM: concat(x, deter_in)[5120] @ Wg -> 12288 partials (Wg cacheable)
    k_gemm<false><<<dim3(24, NSPLIT), 256, 0, stream>>>(
        mkargs(x, HID, HID, din_cur, DET, Wg, 3 * DET, HID + DET, KSG, NSPLIT, Pg));
    // 4) reduce partials -> Sg + per-chunk (sum, sumsq)
    k_red<<<dim3(12, 16), 256, 0, stream>>>(Pg, NSPLIT, Sg, red_s, red_q);
    // 5) obs GEMM with fused gate recompute (tile0 writes deter + din_next)
    k_obsg<<<dim3(2, 32), 256, 0, stream>>>(Sg, red_s, red_q, gg, bg, din_cur, din_next,
                                            init_deter, isf, t, Wo2, out, Pb);
    // 6) obs finish (+OE) -> h2
    k_fin<<<16, 1024, 0, stream>>>(Pb, 32, out + (size_t)t * OUT_C + 5120, OUT_RSTRIDE,
                                   go, bo, h2);
    // 7) post-sample GEMM: h2 @ Wob
    k_gemm<true><<<dim3(2, 16), 256, 0, stream>>>(
        mkargs(h2, HID, HID, nullptr, 0, Wob, SD, HID, 64, 16, Ps1));
    // 8) post sample + next-step blends
    k_samp<<<16, 1024, 0, stream>>>(
        Ps1, 16, bbo, gpost + (size_t)t * SD, (long)T_STEPS * SD,
        out + (size_t)t * OUT_C + 0, OUT_RSTRIDE,
        out + (size_t)t * OUT_C + 5120, OUT_RSTRIDE,
        isf, pa, t, stoch_in, a_eff, init_stoch);
  }

  // ---- deferred prior branch (batched over all (b,t)) ----
  k_mm<<<dim3(16, 16), 256, 0, stream>>>(out + 1024, OUT_C, W2a, DET, h_all, HID, nullptr);
  k_ln_rows<<<1024, 256, 0, stream>>>(h_all, g2, b2);
  k_mm<<<dim3(16, 16), 256, 0, stream>>>(h_all, HID, W2b, HID, out + 7168, OUT_C, bb2);
  k_samp_prior<<<1024, 1024, 0, stream>>>(out, gprior);
}

// Round 10
// 11677.663 us; speedup vs baseline: 2.0199x; 1.0313x over previous
//
#include <hip/hip_runtime.h>
#include <cmath>

// RSSM scan: B=16, T=64, A=6, E=12288, DET=4096, HID=1024, S=32, D=32
// fp32 throughout (argmax stability). Deterministic fixed-order reductions.
// 8 launches/step. NT policy: only Wg is L3-cacheable; all other in-loop
// traffic (partials, Sg, other weights, d_out writes) is nontemporal.

#define B 16
#define T_STEPS 64
#define A_DIM 6
#define E_DIM 12288
#define DET 4096
#define HID 1024
#define SD 1024
#define OUT_C 8192
#define OUT_RSTRIDE (T_STEPS * OUT_C)

typedef float f2v __attribute__((ext_vector_type(2)));
typedef float f4v __attribute__((ext_vector_type(4)));

#define NTL(p) __builtin_nontemporal_load(p)
#define NTS(v, p) __builtin_nontemporal_store(v, p)

// ---------------- block reduce (deterministic) ----------------
__device__ __forceinline__ float block_sum(float v, float* red, int nw) {
#pragma unroll
  for (int m = 32; m >= 1; m >>= 1) v += __shfl_xor(v, m, 64);
  int wid = threadIdx.x >> 6;
  if ((threadIdx.x & 63) == 0) red[wid] = v;
  __syncthreads();
  if (wid == 0) {
    float s = ((int)threadIdx.x < nw) ? red[threadIdx.x] : 0.0f;
#pragma unroll
    for (int m = 8; m >= 1; m >>= 1) s += __shfl_xor(s, m, 16);
    if (threadIdx.x == 0) red[0] = s;
  }
  __syncthreads();
  float out = red[0];
  __syncthreads();
  return out;
}

__global__ __launch_bounds__(1024) void k_tanh(const float* __restrict__ w, float* __restrict__ o) {
  int i = blockIdx.x * 1024 + threadIdx.x;
  if (i < DET) o[i] = tanhf(w[i]);
}

// ---------------- prep (t=0 only) ----------------
__global__ __launch_bounds__(256) void k_prep(
    const float* __restrict__ isf, const float* __restrict__ pa, int t,
    const float* __restrict__ stoch_prev,
    const float* __restrict__ deter_prev, long deter_prev_stride,
    const float* __restrict__ init_stoch, const float* __restrict__ init_deter_row,
    float* __restrict__ stoch_in, float* __restrict__ deter_in, float* __restrict__ a_eff) {
  int r = blockIdx.x;
  float f = isf[r * T_STEPS + t];
  float omf = 1.0f - f;
  for (int c = threadIdx.x; c < SD; c += 256)
    stoch_in[r * SD + c] = stoch_prev[r * SD + c] * omf + init_stoch[r * SD + c] * f;
  for (int c = threadIdx.x; c < DET; c += 256)
    deter_in[r * DET + c] = deter_prev[(long)r * deter_prev_stride + c] * omf + init_deter_row[c] * f;
  if ((int)threadIdx.x < A_DIM) {
    float a = pa[(r * T_STEPS + t) * A_DIM + threadIdx.x];
    a = a * (1.0f / fmaxf(fabsf(a), 1.0f));
    a_eff[r * 8 + threadIdx.x] = a * omf;
  }
}

// ---------------- K-split GEMM: P[split][16][N] partials ----------------
struct GemmArgs {
  const float* A0; long sA0; int cA0;
  const float* A1; long sA1;
  const float* W; int N; int Ktot; int KS; int nsplit;
  float* P;
};

template <bool NT>
__global__ __launch_bounds__(256) void k_gemm(GemmArgs g) {
  if ((int)blockIdx.y >= g.nsplit) return;
  const int tid = threadIdx.x;
  const int c0 = blockIdx.x * 512 + tid * 2;
  const int k0 = (int)blockIdx.y * g.KS;
  __shared__ float in_s[16][64];
  float acc[16][2];
#pragma unroll
  for (int r = 0; r < 16; r++) { acc[r][0] = 0.f; acc[r][1] = 0.f; }
  for (int kb = 0; kb < g.KS; kb += 64) {
    const int kbase = k0 + kb;
#pragma unroll
    for (int j = 0; j < 4; j++) {
      int ii = tid + j * 256;
      int r = ii >> 6, kk = ii & 63;
      int k = kbase + kk;
      float v = 0.f;
      if (k < g.cA0) v = g.A0[(long)r * g.sA0 + k];
      else if (k < g.Ktot) v = g.A1[(long)r * g.sA1 + (k - g.cA0)];
      in_s[r][kk] = v;
    }
    __syncthreads();
    if (kbase + 64 <= g.Ktot) {
      const float* wp = g.W + (size_t)kbase * g.N + c0;
#pragma unroll 4
      for (int kk = 0; kk < 64; kk++) {
        f2v w = NT ? NTL((const f2v*)wp) : *(const f2v*)wp;
        wp += g.N;
#pragma unroll
        for (int r = 0; r < 16; r++) {
          acc[r][0] += in_s[r][kk] * w[0]; acc[r][1] += in_s[r][kk] * w[1];
        }
      }
    } else {  // K tail (img1: Ktot=1030)
#pragma unroll 4
      for (int kk = 0; kk < 64; kk++) {
        int krow = kbase + kk; if (krow >= g.Ktot) krow = g.Ktot - 1;
        const f2v w = *(const f2v*)(g.W + (size_t)krow * g.N + c0);
#pragma unroll
        for (int r = 0; r < 16; r++) {
          acc[r][0] += in_s[r][kk] * w[0]; acc[r][1] += in_s[r][kk] * w[1];
        }
      }
    }
    __syncthreads();
  }
#pragma unroll
  for (int r = 0; r < 16; r++)
    NTS((f2v{acc[r][0], acc[r][1]}), (f2v*)(g.P + ((size_t)blockIdx.y * 16 + r) * g.N + c0));
}

// ---------------- finish: (optional add) + sum partials + LN + silu ----------------
__global__ __launch_bounds__(1024) void k_fin(
    const float* __restrict__ P, int nP,
    const float* __restrict__ add, long ads,
    const float* __restrict__ gv, const float* __restrict__ bv,
    float* __restrict__ o) {
  int r = blockIdx.x, c = threadIdx.x;
  __shared__ float red[18];
  float v = add ? NTL(add + (size_t)r * ads + c) : 0.0f;
  for (int ks = 0; ks < nP; ks++) v += NTL(P + ((size_t)ks * 16 + r) * HID + c);
  float m = block_sum(v, red, 16) * (1.0f / (float)HID);
  float d = v - m;
  float var = block_sum(d * d, red, 16) * (1.0f / (float)HID);
  float rs = 1.0f / sqrtf(var + 1e-3f);
  float y = d * rs * gv[c] + bv[c];
  float s = 1.0f / (1.0f + expf(-y));
  o[r * HID + c] = y * s;
}

// ---------------- init sample (mode) ----------------
__global__ __launch_bounds__(1024) void k_samp_init(
    const float* __restrict__ P, int nP, const float* __restrict__ bb,
    float* __restrict__ st) {
  int r = blockIdx.x, c = threadIdx.x;
  float acc = bb[c];
  for (int ks = 0; ks < nP; ks++) acc += NTL(P + ((size_t)ks * 16 + r) * SD + c);
  int d = c & 31;
  float mx = acc;
#pragma unroll
  for (int m = 16; m >= 1; m >>= 1) mx = fmaxf(mx, __shfl_xor(mx, m, 32));
  float e = expf(acc - mx);
  float se = e;
#pragma unroll
  for (int m = 16; m >= 1; m >>= 1) se += __shfl_xor(se, m, 32);
  float p = 0.99f * (e / se) + 3.125e-4f;
  float by = p; int bi = d;
#pragma unroll
  for (int m = 16; m >= 1; m >>= 1) {
    float oy = __shfl_xor(by, m, 32);
    int oi = __shfl_xor(bi, m, 32);
    if (oy > by || (oy == by && oi < bi)) { by = oy; bi = oi; }
  }
  float oh = (d == bi) ? 1.0f : 0.0f;
  st[r * SD + c] = (oh + p) - p;
}

// ---------------- tiled GEMM: out[M x 1024] = A[M x K] @ Bw[K x 1024] (+bias) ----------
template <bool NTST>
__global__ __launch_bounds__(256) void k_mm(const float* __restrict__ A, long lda,
                                            const float* __restrict__ Bw, int K,
                                            float* __restrict__ out, long ldo,
                                            const float* __restrict__ bias) {
  __shared__ float As[32][68];
  __shared__ float Bs[32][68];
  const int tid = threadIdx.x;
  const int tx = tid & 15, ty = tid >> 4;
  const int row0 = blockIdx.y * 64, col0 = blockIdx.x * 64;
  const int ar = tid >> 2, ak = (tid & 3) * 8;
  const int bk = tid >> 4, bc = (tid & 15) * 4;
  float acc[4][4] = {};
  const float* ap = A + (size_t)(row0 + ar) * lda + ak;
  const float* bp = Bw + (size_t)bk * HID + col0 + bc;
  for (int k0 = 0; k0 < K; k0 += 32) {
    float4 a0 = *(const float4*)(ap + k0);
    float4 a1 = *(const float4*)(ap + k0 + 4);
    float4 b0 = *(const float4*)(bp + (size_t)k0 * HID);
    float4 b1 = *(const float4*)(bp + (size_t)(k0 + 16) * HID);
    __syncthreads();
    As[ak + 0][ar] = a0.x; As[ak + 1][ar] = a0.y; As[ak + 2][ar] = a0.z; As[ak + 3][ar] = a0.w;
    As[ak + 4][ar] = a1.x; As[ak + 5][ar] = a1.y; As[ak + 6][ar] = a1.z; As[ak + 7][ar] = a1.w;
    *(float4*)&Bs[bk][bc] = b0;
    *(float4*)&Bs[bk + 16][bc] = b1;
    __syncthreads();
#pragma unroll
    for (int kk = 0; kk < 32; kk++) {
      float4 av = *(const float4*)&As[kk][ty * 4];
      float4 bv = *(const float4*)&Bs[kk][tx * 4];
      acc[0][0] += av.x * bv.x; acc[0][1] += av.x * bv.y; acc[0][2] += av.x * bv.z; acc[0][3] += av.x * bv.w;
      acc[1][0] += av.y * bv.x; acc[1][1] += av.y * bv.y; acc[1][2] += av.y * bv.z; acc[1][3] += av.y * bv.w;
      acc[2][0] += av.z * bv.x; acc[2][1] += av.z * bv.y; acc[2][2] += av.z * bv.z; acc[2][3] += av.z * bv.w;
      acc[3][0] += av.w * bv.x; acc[3][1] += av.w * bv.y; acc[3][2] += av.w * bv.z; acc[3][3] += av.w * bv.w;
    }
  }
#pragma unroll
  for (int i = 0; i < 4; i++) {
    int col = col0 + tx * 4;
    f4v o;
    o[0] = acc[i][0] + (bias ? bias[col + 0] : 0.f);
    o[1] = acc[i][1] + (bias ? bias[col + 1] : 0.f);
    o[2] = acc[i][2] + (bias ? bias[col + 2] : 0.f);
    o[3] = acc[i][3] + (bias ? bias[col + 3] : 0.f);
    float* dst = out + (size_t)(row0 + ty * 4 + i) * ldo + col;
    if (NTST) NTS(o, (f4v*)dst);
    else *(f4v*)dst = o;
  }
}

// ---------------- deferred: per-row LN + silu in place ----------------
__global__ __launch_bounds__(256) void k_ln_rows(float* __restrict__ h,
                                                 const float* __restrict__ gv,
                                                 const float* __restrict__ bv) {
  int row = blockIdx.x, c0 = threadIdx.x * 4;
  __shared__ float red[18];
  float4 v = *(const float4*)(h + (size_t)row * HID + c0);
  float lsum = (v.x + v.y) + (v.z + v.w);
  float m = block_sum(lsum, red, 4) * (1.0f / (float)HID);
  float dx = v.x - m, dy = v.y - m, dz = v.z - m, dw = v.w - m;
  float lv = (dx * dx + dy * dy) + (dz * dz + dw * dw);
  float var = block_sum(lv, red, 4) * (1.0f / (float)HID);
  float rs = 1.0f / sqrtf(var + 1e-3f);
  float4 o;
  float y0 = dx * rs * gv[c0] + bv[c0];         o.x = y0 / (1.0f + expf(-y0));
  float y1 = dy * rs * gv[c0 + 1] + bv[c0 + 1]; o.y = y1 / (1.0f + expf(-y1));
  float y2 = dz * rs * gv[c0 + 2] + bv[c0 + 2]; o.z = y2 / (1.0f + expf(-y2));
  float y3 = dw * rs * gv[c0 + 3] + bv[c0 + 3]; o.w = y3 / (1.0f + expf(-y3));
  *(float4*)(h + (size_t)row * HID + c0) = o;
}

// ---------------- deferred: batched prior sample (logits in out+7168) ----------------
__global__ __launch_bounds__(1024) void k_samp_prior(float* __restrict__ out,
                                                     const float* __restrict__ gum) {
  int m = blockIdx.x, c = threadIdx.x;
  float lp = out[(size_t)m * OUT_C + 7168 + c];
  int d = c & 31;
  float mx = lp;
#pragma unroll
  for (int mm = 16; mm >= 1; mm >>= 1) mx = fmaxf(mx, __shfl_xor(mx, mm, 32));
  float e = expf(lp - mx);
  float se = e;
#pragma unroll
  for (int mm = 16; mm >= 1; mm >>= 1) se += __shfl_xor(se, mm, 32);
  float p = 0.99f * (e / se) + 3.125e-4f;
  float y = logf(p) + gum[(size_t)m * SD + c];
  float by = y; int bi = d;
#pragma unroll
  for (int mm = 16; mm >= 1; mm >>= 1) {
    float oy = __shfl_xor(by, mm, 32);
    int oi = __shfl_xor(bi, mm, 32);
    if (oy > by || (oy == by && oi < bi)) { by = oy; bi = oi; }
  }
  float oh = (d == bi) ? 1.0f : 0.0f;
  out[(size_t)m * OUT_C + 6144 + c] = (oh + p) - p;
}

// ---------------- GRU stage-1 reduce: sum splits + (sum, sumsq) per chunk ----------
__global__ __launch_bounds__(256) void k_red(const float* __restrict__ P, int nP,
                                             float* __restrict__ S,
                                             float* __restrict__ red_s, float* __restrict__ red_q) {
  int chunk = blockIdx.x, r = blockIdx.y;
  int c = chunk * 1024 + threadIdx.x * 4;
  f4v s = {0, 0, 0, 0};
  for (int ks = 0; ks < nP; ks++) {
    f4v v = NTL((const f4v*)(P + ((size_t)ks * 16 + r) * (3 * DET) + c));
    s[0] += v[0]; s[1] += v[1]; s[2] += v[2]; s[3] += v[3];
  }
  NTS(s, (f4v*)(S + (size_t)r * (3 * DET) + c));
  float sx = (s[0] + s[1]) + (s[2] + s[3]);
  float sq = (s[0] * s[0] + s[1] * s[1]) + (s[2] * s[2] + s[3] * s[3]);
  __shared__ float rbuf[8];
#pragma unroll
  for (int m = 32; m >= 1; m >>= 1) { sx += __shfl_xor(sx, m, 64); sq += __shfl_xor(sq, m, 64); }
  int wid = threadIdx.x >> 6;
  if ((threadIdx.x & 63) == 0) { rbuf[wid] = sx; rbuf[4 + wid] = sq; }
  __syncthreads();
  if (threadIdx.x == 0) {
    red_s[r * 12 + chunk] = (rbuf[0] + rbuf[1]) + (rbuf[2] + rbuf[3]);
    red_q[r * 12 + chunk] = (rbuf[4] + rbuf[5]) + (rbuf[6] + rbuf[7]);
  }
}

// ---- obs GEMM with fused GRU-gate recompute (per 128-col K-slice; no fence) ----
__global__ __launch_bounds__(256) void k_obsg(
    const float* __restrict__ Sg, const float* __restrict__ red_s, const float* __restrict__ red_q,
    const float* __restrict__ gg, const float* __restrict__ bg,
    const float* __restrict__ din_cur, float* __restrict__ din_next,
    const float* __restrict__ init_deter, const float* __restrict__ isf, int t,
    const float* __restrict__ W,
    float* __restrict__ out, float* __restrict__ P) {
  const int tid = threadIdx.x;
  const int tile = blockIdx.x;       // 0..1 (col half)
  const int split = blockIdx.y;      // 0..31 (K slice of 128)
  const int c0 = tile * 512 + tid * 2;
  const int j0 = split * 128;
  __shared__ float dn_s[16][128];
  __shared__ float mvf[16][3];
  if (tid < 16) {
    int r = tid;
    float s = 0.f, q = 0.f;
    for (int k2 = 0; k2 < 12; k2++) { s += red_s[r * 12 + k2]; q += red_q[r * 12 + k2]; }
    float m = s * (1.0f / (float)(3 * DET));
    float var = q * (1.0f / (float)(3 * DET)) - m * m;
    mvf[r][0] = m; mvf[r][1] = 1.0f / sqrtf(var + 1e-3f);
    mvf[r][2] = (t + 1 < T_STEPS) ? isf[r * T_STEPS + t + 1] : 0.0f;
  }
  __syncthreads();
  for (int e = tid; e < 16 * 128; e += 256) {
    int r = e >> 7, jj = e & 127;
    int j = j0 + jj;
    float m = mvf[r][0], rs = mvf[r][1];
    const float* Sr = Sg + (size_t)r * (3 * DET);
    float lr = (NTL(Sr + j) - m) * rs * gg[j] + bg[j];
    float lc = (NTL(Sr + j + DET) - m) * rs * gg[j + DET] + bg[j + DET];
    float lu = (NTL(Sr + j + 2 * DET) - m) * rs * gg[j + 2 * DET] + bg[j + 2 * DET];
    float rr = 1.0f / (1.0f + expf(-lr));
    float cd = tanhf(rr * lc);
    float uu = 1.0f / (1.0f + expf(-(lu - 1.0f)));
    float dn = uu * cd + (1.0f - uu) * din_cur[r * DET + j];
    dn_s[r][jj] = dn;
    if (tile == 0) {
      NTS(dn, out + (size_t)(r * T_STEPS + t) * OUT_C + 1024 + j);
      float ft = mvf[r][2];
      din_next[r * DET + j] = dn * (1.0f - ft) + init_deter[j] * ft;
    }
  }
  __syncthreads();
  float acc[16][2];
#pragma unroll
  for (int r = 0; r < 16; r++) { acc[r][0] = 0.f; acc[r][1] = 0.f; }
  for (int kb = 0; kb < 128; kb += 64) {
    const float* wp = W + (size_t)(j0 + kb) * HID + c0;
#pragma unroll 4
    for (int kk = 0; kk < 64; kk++) {
      f2v w = NTL((const f2v*)wp);
      wp += HID;
#pragma unroll
      for (int r = 0; r < 16; r++) {
        float iv = dn_s[r][kb + kk];
        acc[r][0] += iv * w[0]; acc[r][1] += iv * w[1];
      }
    }
  }
#pragma unroll
  for (int r = 0; r < 16; r++)
    NTS((f2v{acc[r][0], acc[r][1]}), (f2v*)(P + ((size_t)split * 16 + r) * HID + c0));
}

// ---------------- post sample + next-step stoch/a blend ----------------
__global__ __launch_bounds__(1024) void k_samp(
    const float* __restrict__ P, int nP, const float* __restrict__ bb,
    const float* __restrict__ gum, long gs,
    float* __restrict__ st, long ss, float* __restrict__ lg, long ls,
    const float* __restrict__ isf, const float* __restrict__ pa, int t,
    float* __restrict__ stoch_in, float* __restrict__ a_eff,
    const float* __restrict__ init_stoch) {
  int r = blockIdx.x, c = threadIdx.x;
  float acc = bb[c];
  for (int ks = 0; ks < nP; ks++) acc += NTL(P + ((size_t)ks * 16 + r) * SD + c);
  int d = c & 31;
  float mx = acc;
#pragma unroll
  for (int m = 16; m >= 1; m >>= 1) mx = fmaxf(mx, __shfl_xor(mx, m, 32));
  float e = expf(acc - mx);
  float se = e;
#pragma unroll
  for (int m = 16; m >= 1; m >>= 1) se += __shfl_xor(se, m, 32);
  float p = 0.99f * (e / se) + 3.125e-4f;
  float y = logf(p) + gum[(long)r * gs + c];
  float by = y; int bi = d;
#pragma unroll
  for (int m = 16; m >= 1; m >>= 1) {
    float oy = __shfl_xor(by, m, 32);
    int oi = __shfl_xor(bi, m, 32);
    if (oy > by || (oy == by && oi < bi)) { by = oy; bi = oi; }
  }
  float oh = (d == bi) ? 1.0f : 0.0f;
  float outv = (oh + p) - p;
  NTS(outv, st + (long)r * ss + c);
  NTS(acc, lg + (long)r * ls + c);
  float fn = (t + 1 < T_STEPS) ? isf[r * T_STEPS + t + 1] : 0.0f;
  stoch_in[r * SD + c] = outv * (1.0f - fn) + init_stoch[r * SD + c] * fn;
  if (c < A_DIM) {
    float a = (t + 1 < T_STEPS) ? pa[(r * T_STEPS + t + 1) * A_DIM + c] : 0.0f;
    a = a * (1.0f / fmaxf(fabsf(a), 1.0f));
    a_eff[r * 8 + c] = a * (1.0f - fn);
  }
}

// ---------------- host ----------------
static inline GemmArgs mkargs(const float* A0, long sA0, int cA0,
                              const float* A1, long sA1,
                              const float* W, int N, int Ktot, int KS, int nsplit, float* P) {
  GemmArgs g; g.A0 = A0; g.sA0 = sA0; g.cA0 = cA0; g.A1 = A1; g.sA1 = sA1;
  g.W = W; g.N = N; g.Ktot = Ktot; g.KS = KS; g.nsplit = nsplit; g.P = P;
  return g;
}

extern "C" void kernel_launch(void* const* d_in, const int* in_sizes, int n_in,
                              void* d_out, int out_size, void* d_ws, size_t ws_size,
                              hipStream_t stream) {
  const float* embed  = (const float*)d_in[0];
  const float* pa     = (const float*)d_in[1];
  const float* isf    = (const float*)d_in[2];
  const float* gprior = (const float*)d_in[3];
  const float* gpost  = (const float*)d_in[4];
  const float* w_init = (const float*)d_in[5];
  const float* W1  = (const float*)d_in[6];
  const float* g1  = (const float*)d_in[7];
  const float* b1  = (const float*)d_in[8];
  const float* Wg  = (const float*)d_in[9];
  const float* gg  = (const float*)d_in[10];
  const float* bg  = (const float*)d_in[11];
  const float* W2a = (const float*)d_in[12];
  const float* g2  = (const float*)d_in[13];
  const float* b2  = (const float*)d_in[14];
  const float* W2b = (const float*)d_in[15];
  const float* bb2 = (const float*)d_in[16];
  const float* Wo  = (const float*)d_in[17];
  const float* go  = (const float*)d_in[18];
  const float* bo  = (const float*)d_in[19];
  const float* Wob = (const float*)d_in[20];
  const float* bbo = (const float*)d_in[21];
  float* out = (float*)d_out;
  float* ws  = (float*)d_ws;

  // workspace (floats) — round-6 validated layout
  float* Pg    = ws;                    // 20*16*12288 = 3,932,160 (aliased: h_all deferred)
  float* h_all = Pg;                    // 1024*1024
  float* Sg    = Pg + 3932160;          // 196,608
  float* red_s = Sg + 196608;           // 192
  float* red_q = red_s + 192;           // 192 (+pad)
  float* Pimg1 = red_s + 512;           // 17*16*1024 = 278,528
  float* Pb    = Pimg1 + 278528;        // 32*16*1024 = 524,288
  float* Ps1   = Pb + 524288;           // 16*16*1024 = 262,144
  float* st_   = Ps1 + 262144;
  float* init_stoch = st_;              // 16,384
  float* init_deter = st_ + 16384;      // 4,096
  float* stoch_in   = st_ + 20480;      // 16,384
  float* din0       = st_ + 36864;      // 65,536
  float* din1       = st_ + 102400;     // 65,536
  float* a_eff      = st_ + 167936;     // 128
  float* x          = st_ + 168064;     // 16,384
  float* h2         = st_ + 184448;     // 16,384

  // ---- OE precompute: e @ Wo[0:E] -> out post-logit slots (NT stores keep L3 clean)
  k_mm<true><<<dim3(16, 16), 256, 0, stream>>>(embed, E_DIM, Wo, E_DIM, out + 5120, OUT_C, nullptr);

  // ---- init: init_deter = tanh(w_init); init_stoch = st_mode(prior_logits(init_deter))
  k_tanh<<<4, 1024, 0, stream>>>(w_init, init_deter);
  k_gemm<true><<<dim3(2, 32), 256, 0, stream>>>(
      mkargs(init_deter, 0, DET, nullptr, 0, W2a, HID, DET, 128, 32, Pb));
  k_fin<<<16, 1024, 0, stream>>>(Pb, 32, nullptr, 0, g2, b2, x);
  k_gemm<true><<<dim3(2, 16), 256, 0, stream>>>(
      mkargs(x, HID, HID, nullptr, 0, W2b, SD, HID, 64, 16, Ps1));
  k_samp_init<<<16, 1024, 0, stream>>>(Ps1, 16, bb2, init_stoch);

  // ---- t=0 prep (f[:,0]==1 -> all init) ----
  k_prep<<<16, 256, 0, stream>>>(isf, pa, 0, init_stoch, init_deter, 0,
                                 init_stoch, init_deter, stoch_in, din0, a_eff);

  const float* Wo2 = Wo + (size_t)E_DIM * HID;
  for (int t = 0; t < T_STEPS; t++) {
    float* din_cur  = (t & 1) ? din1 : din0;
    float* din_next = (t & 1) ? din0 : din1;
    // 1) img1 GEMM: concat(stoch,a)[1030] @ W1 -> 1024 partials
    k_gemm<true><<<dim3(2, 17), 256, 0, stream>>>(
        mkargs(stoch_in, SD, SD, a_eff, 8, W1, HID, SD + A_DIM, 64, 17, Pimg1));
    // 2) img1 finish -> x
    k_fin<<<16, 1024, 0, stream>>>(Pimg1, 17, nullptr, 0, g1, b1, x);
    // 3) GRU GEMM: concat(x, deter_in)[5120] @ Wg -> 12288 partials (Wg L3-cacheable)
    k_gemm<false><<<dim3(24, 20), 256, 0, stream>>>(
        mkargs(x, HID, HID, din_cur, DET, Wg, 3 * DET, HID + DET, 256, 20, Pg));
    // 4) reduce partials -> Sg + per-chunk (sum, sumsq)
    k_red<<<dim3(12, 16), 256, 0, stream>>>(Pg, 20, Sg, red_s, red_q);
    // 5) obs GEMM with fused gate recompute (tile0 writes deter + din_next)
    k_obsg<<<dim3(2, 32), 256, 0, stream>>>(Sg, red_s, red_q, gg, bg, din_cur, din_next,
                                            init_deter, isf, t, Wo2, out, Pb);
    // 6) obs finish (+OE) -> h2
    k_fin<<<16, 1024, 0, stream>>>(Pb, 32, out + (size_t)t * OUT_C + 5120, OUT_RSTRIDE,
                                   go, bo, h2);
    // 7) post-sample GEMM: h2 @ Wob
    k_gemm<true><<<dim3(2, 16), 256, 0, stream>>>(
        mkargs(h2, HID, HID, nullptr, 0, Wob, SD, HID, 64, 16, Ps1));
    // 8) post sample + next-step blends
    k_samp<<<16, 1024, 0, stream>>>(
        Ps1, 16, bbo, gpost + (size_t)t * SD, (long)T_STEPS * SD,
        out + (size_t)t * OUT_C + 0, OUT_RSTRIDE,
        out + (size_t)t * OUT_C + 5120, OUT_RSTRIDE,
        isf, pa, t, stoch_in, a_eff, init_stoch);
  }

  // ---- deferred prior branch (batched over all (b,t)) ----
  k_mm<false><<<dim3(16, 16), 256, 0, stream>>>(out + 1024, OUT_C, W2a, DET, h_all, HID, nullptr);
  k_ln_rows<<<1024, 256, 0, stream>>>(h_all, g2, b2);
  k_mm<false><<<dim3(16, 16), 256, 0, stream>>>(h_all, HID, W2b, HID, out + 7168, OUT_C, bb2);
  k_samp_prior<<<1024, 1024, 0, stream>>>(out, gprior);
}

// Round 11
// 10489.998 us; speedup vs baseline: 2.2486x; 1.1132x over previous
//
#include <hip/hip_runtime.h>
#include <cmath>

// RSSM scan: B=16, T=64, A=6, E=12288, DET=4096, HID=1024, S=32, D=32
// fp32 throughout (argmax stability). Deterministic fixed-order reductions.
// 8 launches/step: img1G, img1F, gruG, red, obs+prior G (gate fused, z-batched),
// fin2(batched), sampG(z-batched), samp(batched prior+post).
// NT policy (r3-validated): NT only non-Wg weight streams; partials/Sg normal.

#define B 16
#define T_STEPS 64
#define A_DIM 6
#define E_DIM 12288
#define DET 4096
#define HID 1024
#define SD 1024
#define OUT_C 8192
#define OUT_RSTRIDE (T_STEPS * OUT_C)

typedef float f2v __attribute__((ext_vector_type(2)));
typedef float f4v __attribute__((ext_vector_type(4)));

#define NTL(p) __builtin_nontemporal_load(p)

// ---------------- block reduce (deterministic) ----------------
__device__ __forceinline__ float block_sum(float v, float* red, int nw) {
#pragma unroll
  for (int m = 32; m >= 1; m >>= 1) v += __shfl_xor(v, m, 64);
  int wid = threadIdx.x >> 6;
  if ((threadIdx.x & 63) == 0) red[wid] = v;
  __syncthreads();
  if (wid == 0) {
    float s = ((int)threadIdx.x < nw) ? red[threadIdx.x] : 0.0f;
#pragma unroll
    for (int m = 8; m >= 1; m >>= 1) s += __shfl_xor(s, m, 16);
    if (threadIdx.x == 0) red[0] = s;
  }
  __syncthreads();
  float out = red[0];
  __syncthreads();
  return out;
}

__global__ __launch_bounds__(1024) void k_tanh(const float* __restrict__ w, float* __restrict__ o) {
  int i = blockIdx.x * 1024 + threadIdx.x;
  if (i < DET) o[i] = tanhf(w[i]);
}

// ---------------- prep (t=0 only) ----------------
__global__ __launch_bounds__(256) void k_prep(
    const float* __restrict__ isf, const float* __restrict__ pa, int t,
    const float* __restrict__ stoch_prev,
    const float* __restrict__ deter_prev, long deter_prev_stride,
    const float* __restrict__ init_stoch, const float* __restrict__ init_deter_row,
    float* __restrict__ stoch_in, float* __restrict__ deter_in, float* __restrict__ a_eff) {
  int r = blockIdx.x;
  float f = isf[r * T_STEPS + t];
  float omf = 1.0f - f;
  for (int c = threadIdx.x; c < SD; c += 256)
    stoch_in[r * SD + c] = stoch_prev[r * SD + c] * omf + init_stoch[r * SD + c] * f;
  for (int c = threadIdx.x; c < DET; c += 256)
    deter_in[r * DET + c] = deter_prev[(long)r * deter_prev_stride + c] * omf + init_deter_row[c] * f;
  if ((int)threadIdx.x < A_DIM) {
    float a = pa[(r * T_STEPS + t) * A_DIM + threadIdx.x];
    a = a * (1.0f / fmaxf(fabsf(a), 1.0f));
    a_eff[r * 8 + threadIdx.x] = a * omf;
  }
}

// ---------------- K-split GEMM: P[split][16][N] partials (z-batched) ----------------
struct GemmArgs {
  const float* A0; long sA0; int cA0;
  const float* A1; long sA1;
  const float* W; int N; int Ktot; int KS; int nsplit;
  float* P;
};

template <bool NT>
__global__ __launch_bounds__(256) void k_gemm(GemmArgs ga, GemmArgs gb) {
  const GemmArgs g = blockIdx.z ? gb : ga;
  if ((int)blockIdx.y >= g.nsplit) return;
  const int tid = threadIdx.x;
  const int c0 = blockIdx.x * 512 + tid * 2;
  const int k0 = (int)blockIdx.y * g.KS;
  __shared__ float in_s[16][64];
  float acc[16][2];
#pragma unroll
  for (int r = 0; r < 16; r++) { acc[r][0] = 0.f; acc[r][1] = 0.f; }
  for (int kb = 0; kb < g.KS; kb += 64) {
    const int kbase = k0 + kb;
#pragma unroll
    for (int j = 0; j < 4; j++) {
      int ii = tid + j * 256;
      int r = ii >> 6, kk = ii & 63;
      int k = kbase + kk;
      float v = 0.f;
      if (k < g.cA0) v = g.A0[(long)r * g.sA0 + k];
      else if (k < g.Ktot) v = g.A1[(long)r * g.sA1 + (k - g.cA0)];
      in_s[r][kk] = v;
    }
    __syncthreads();
    if (kbase + 64 <= g.Ktot) {
      const float* wp = g.W + (size_t)kbase * g.N + c0;
#pragma unroll 4
      for (int kk = 0; kk < 64; kk++) {
        f2v w = NT ? NTL((const f2v*)wp) : *(const f2v*)wp;
        wp += g.N;
#pragma unroll
        for (int r = 0; r < 16; r++) {
          acc[r][0] += in_s[r][kk] * w[0]; acc[r][1] += in_s[r][kk] * w[1];
        }
      }
    } else {  // K tail (img1: Ktot=1030)
#pragma unroll 4
      for (int kk = 0; kk < 64; kk++) {
        int krow = kbase + kk; if (krow >= g.Ktot) krow = g.Ktot - 1;
        const f2v w = *(const f2v*)(g.W + (size_t)krow * g.N + c0);
#pragma unroll
        for (int r = 0; r < 16; r++) {
          acc[r][0] += in_s[r][kk] * w[0]; acc[r][1] += in_s[r][kk] * w[1];
        }
      }
    }
    __syncthreads();
  }
#pragma unroll
  for (int r = 0; r < 16; r++)
    *(f2v*)(g.P + ((size_t)blockIdx.y * 16 + r) * g.N + c0) = f2v{acc[r][0], acc[r][1]};
}

// ---------------- batched finish: (optional add) + sum partials + LN + silu ----------
__global__ __launch_bounds__(1024) void k_fin2(
    const float* __restrict__ Pa_, int nPa, const float* __restrict__ addA, long adsA,
    const float* __restrict__ gva, const float* __restrict__ bva, float* __restrict__ oa,
    const float* __restrict__ Pb_, int nPb, const float* __restrict__ addB, long adsB,
    const float* __restrict__ gvb, const float* __restrict__ bvb, float* __restrict__ ob) {
  int which = blockIdx.x >> 4, r = blockIdx.x & 15, c = threadIdx.x;
  const float* P = which ? Pb_ : Pa_;
  int nP = which ? nPb : nPa;
  const float* add = which ? addB : addA;
  long ads = which ? adsB : adsA;
  const float* gv = which ? gvb : gva;
  const float* bv = which ? bvb : bva;
  float* o = which ? ob : oa;
  __shared__ float red[18];
  float v = add ? add[(size_t)r * ads + c] : 0.0f;
  for (int ks = 0; ks < nP; ks++) v += P[((size_t)ks * 16 + r) * HID + c];
  float m = block_sum(v, red, 16) * (1.0f / (float)HID);
  float d = v - m;
  float var = block_sum(d * d, red, 16) * (1.0f / (float)HID);
  float rs = 1.0f / sqrtf(var + 1e-3f);
  float y = d * rs * gv[c] + bv[c];
  float s = 1.0f / (1.0f + expf(-y));
  o[r * HID + c] = y * s;
}

// ---------------- init sample (mode) ----------------
__global__ __launch_bounds__(1024) void k_samp_init(
    const float* __restrict__ P, int nP, const float* __restrict__ bb,
    float* __restrict__ st) {
  int r = blockIdx.x, c = threadIdx.x;
  float acc = bb[c];
  for (int ks = 0; ks < nP; ks++) acc += P[((size_t)ks * 16 + r) * SD + c];
  int d = c & 31;
  float mx = acc;
#pragma unroll
  for (int m = 16; m >= 1; m >>= 1) mx = fmaxf(mx, __shfl_xor(mx, m, 32));
  float e = expf(acc - mx);
  float se = e;
#pragma unroll
  for (int m = 16; m >= 1; m >>= 1) se += __shfl_xor(se, m, 32);
  float p = 0.99f * (e / se) + 3.125e-4f;
  float by = p; int bi = d;
#pragma unroll
  for (int m = 16; m >= 1; m >>= 1) {
    float oy = __shfl_xor(by, m, 32);
    int oi = __shfl_xor(bi, m, 32);
    if (oy > by || (oy == by && oi < bi)) { by = oy; bi = oi; }
  }
  float oh = (d == bi) ? 1.0f : 0.0f;
  st[r * SD + c] = (oh + p) - p;
}

// ---------------- tiled GEMM (OE precompute): out[M x 1024] = A @ Bw ----------
__global__ __launch_bounds__(256) void k_mm(const float* __restrict__ A, long lda,
                                            const float* __restrict__ Bw, int K,
                                            float* __restrict__ out, long ldo) {
  __shared__ float As[32][68];
  __shared__ float Bs[32][68];
  const int tid = threadIdx.x;
  const int tx = tid & 15, ty = tid >> 4;
  const int row0 = blockIdx.y * 64, col0 = blockIdx.x * 64;
  const int ar = tid >> 2, ak = (tid & 3) * 8;
  const int bk = tid >> 4, bc = (tid & 15) * 4;
  float acc[4][4] = {};
  const float* ap = A + (size_t)(row0 + ar) * lda + ak;
  const float* bp = Bw + (size_t)bk * HID + col0 + bc;
  for (int k0 = 0; k0 < K; k0 += 32) {
    float4 a0 = *(const float4*)(ap + k0);
    float4 a1 = *(const float4*)(ap + k0 + 4);
    float4 b0 = *(const float4*)(bp + (size_t)k0 * HID);
    float4 b1 = *(const float4*)(bp + (size_t)(k0 + 16) * HID);
    __syncthreads();
    As[ak + 0][ar] = a0.x; As[ak + 1][ar] = a0.y; As[ak + 2][ar] = a0.z; As[ak + 3][ar] = a0.w;
    As[ak + 4][ar] = a1.x; As[ak + 5][ar] = a1.y; As[ak + 6][ar] = a1.z; As[ak + 7][ar] = a1.w;
    *(float4*)&Bs[bk][bc] = b0;
    *(float4*)&Bs[bk + 16][bc] = b1;
    __syncthreads();
#pragma unroll
    for (int kk = 0; kk < 32; kk++) {
      float4 av = *(const float4*)&As[kk][ty * 4];
      float4 bv = *(const float4*)&Bs[kk][tx * 4];
      acc[0][0] += av.x * bv.x; acc[0][1] += av.x * bv.y; acc[0][2] += av.x * bv.z; acc[0][3] += av.x * bv.w;
      acc[1][0] += av.y * bv.x; acc[1][1] += av.y * bv.y; acc[1][2] += av.y * bv.z; acc[1][3] += av.y * bv.w;
      acc[2][0] += av.z * bv.x; acc[2][1] += av.z * bv.y; acc[2][2] += av.z * bv.z; acc[2][3] += av.z * bv.w;
      acc[3][0] += av.w * bv.x; acc[3][1] += av.w * bv.y; acc[3][2] += av.w * bv.z; acc[3][3] += av.w * bv.w;
    }
  }
#pragma unroll
  for (int i = 0; i < 4; i++) {
    int col = col0 + tx * 4;
    float4 o;
    o.x = acc[i][0]; o.y = acc[i][1]; o.z = acc[i][2]; o.w = acc[i][3];
    *(float4*)(out + (size_t)(row0 + ty * 4 + i) * ldo + col) = o;
  }
}

// ---------------- GRU stage-1 reduce: sum splits + (sum, sumsq) per chunk ----------
__global__ __launch_bounds__(256) void k_red(const float* __restrict__ P, int nP,
                                             float* __restrict__ S,
                                             float* __restrict__ red_s, float* __restrict__ red_q) {
  int chunk = blockIdx.x, r = blockIdx.y;
  int c = chunk * 1024 + threadIdx.x * 4;
  float4 s = {0, 0, 0, 0};
  for (int ks = 0; ks < nP; ks++) {
    float4 v = *(const float4*)(P + ((size_t)ks * 16 + r) * (3 * DET) + c);
    s.x += v.x; s.y += v.y; s.z += v.z; s.w += v.w;
  }
  *(float4*)(S + (size_t)r * (3 * DET) + c) = s;
  float sx = (s.x + s.y) + (s.z + s.w);
  float sq = (s.x * s.x + s.y * s.y) + (s.z * s.z + s.w * s.w);
  __shared__ float rbuf[8];
#pragma unroll
  for (int m = 32; m >= 1; m >>= 1) { sx += __shfl_xor(sx, m, 64); sq += __shfl_xor(sq, m, 64); }
  int wid = threadIdx.x >> 6;
  if ((threadIdx.x & 63) == 0) { rbuf[wid] = sx; rbuf[4 + wid] = sq; }
  __syncthreads();
  if (threadIdx.x == 0) {
    red_s[r * 12 + chunk] = (rbuf[0] + rbuf[1]) + (rbuf[2] + rbuf[3]);
    red_q[r * 12 + chunk] = (rbuf[4] + rbuf[5]) + (rbuf[6] + rbuf[7]);
  }
}

// ---- obs+prior GEMM with fused GRU-gate recompute (z-batched, per 128-col K-slice) ----
// z=0: obs (W=Wo2 -> Pb); z=1: prior (W=W2a -> Pa). z0/tile0 writes deter + din_next.
__global__ __launch_bounds__(256) void k_obsg2(
    const float* __restrict__ Sg, const float* __restrict__ red_s, const float* __restrict__ red_q,
    const float* __restrict__ gg, const float* __restrict__ bg,
    const float* __restrict__ din_cur, float* __restrict__ din_next,
    const float* __restrict__ init_deter, const float* __restrict__ isf, int t,
    const float* __restrict__ W0, float* __restrict__ P0,
    const float* __restrict__ W1p, float* __restrict__ P1p,
    float* __restrict__ out) {
  const int tid = threadIdx.x;
  const int tile = blockIdx.x;       // 0..1 (col half)
  const int split = blockIdx.y;      // 0..31 (K slice of 128)
  const int z = blockIdx.z;
  const float* W = z ? W1p : W0;
  float* P = z ? P1p : P0;
  const int c0 = tile * 512 + tid * 2;
  const int j0 = split * 128;
  __shared__ float dn_s[16][128];
  __shared__ float mvf[16][3];
  if (tid < 16) {
    int r = tid;
    float s = 0.f, q = 0.f;
    for (int k2 = 0; k2 < 12; k2++) { s += red_s[r * 12 + k2]; q += red_q[r * 12 + k2]; }
    float m = s * (1.0f / (float)(3 * DET));
    float var = q * (1.0f / (float)(3 * DET)) - m * m;
    mvf[r][0] = m; mvf[r][1] = 1.0f / sqrtf(var + 1e-3f);
    mvf[r][2] = (t + 1 < T_STEPS) ? isf[r * T_STEPS + t + 1] : 0.0f;
  }
  __syncthreads();
  for (int e = tid; e < 16 * 128; e += 256) {
    int r = e >> 7, jj = e & 127;
    int j = j0 + jj;
    float m = mvf[r][0], rs = mvf[r][1];
    const float* Sr = Sg + (size_t)r * (3 * DET);
    float lr = (Sr[j] - m) * rs * gg[j] + bg[j];
    float lc = (Sr[j + DET] - m) * rs * gg[j + DET] + bg[j + DET];
    float lu = (Sr[j + 2 * DET] - m) * rs * gg[j + 2 * DET] + bg[j + 2 * DET];
    float rr = 1.0f / (1.0f + expf(-lr));
    float cd = tanhf(rr * lc);
    float uu = 1.0f / (1.0f + expf(-(lu - 1.0f)));
    float dn = uu * cd + (1.0f - uu) * din_cur[r * DET + j];
    dn_s[r][jj] = dn;
    if (z == 0 && tile == 0) {
      out[(size_t)(r * T_STEPS + t) * OUT_C + 1024 + j] = dn;
      float ft = mvf[r][2];
      din_next[r * DET + j] = dn * (1.0f - ft) + init_deter[j] * ft;
    }
  }
  __syncthreads();
  float acc[16][2];
#pragma unroll
  for (int r = 0; r < 16; r++) { acc[r][0] = 0.f; acc[r][1] = 0.f; }
  for (int kb = 0; kb < 128; kb += 64) {
    const float* wp = W + (size_t)(j0 + kb) * HID + c0;
#pragma unroll 4
    for (int kk = 0; kk < 64; kk++) {
      f2v w = NTL((const f2v*)wp);
      wp += HID;
#pragma unroll
      for (int r = 0; r < 16; r++) {
        float iv = dn_s[r][kb + kk];
        acc[r][0] += iv * w[0]; acc[r][1] += iv * w[1];
      }
    }
  }
#pragma unroll
  for (int r = 0; r < 16; r++)
    *(f2v*)(P + ((size_t)split * 16 + r) * HID + c0) = f2v{acc[r][0], acc[r][1]};
}

// ---------------- batched sample: prior (which=0) + post (which=1, blends) ----------
__global__ __launch_bounds__(1024) void k_samp2(
    const float* __restrict__ P0, const float* __restrict__ bb0,
    const float* __restrict__ gum0, long gs0,
    const float* __restrict__ P1, const float* __restrict__ bb1,
    const float* __restrict__ gum1, long gs1,
    float* __restrict__ out, int t, int nP,
    const float* __restrict__ isf, const float* __restrict__ pa,
    float* __restrict__ stoch_in, float* __restrict__ a_eff,
    const float* __restrict__ init_stoch) {
  int which = blockIdx.x >> 4, r = blockIdx.x & 15, c = threadIdx.x;
  const float* P = which ? P1 : P0;
  const float* bbv = which ? bb1 : bb0;
  const float* gum = which ? gum1 : gum0;
  long gs = which ? gs1 : gs0;
  float acc = bbv[c];
  for (int ks = 0; ks < nP; ks++) acc += P[((size_t)ks * 16 + r) * SD + c];
  int d = c & 31;
  float mx = acc;
#pragma unroll
  for (int m = 16; m >= 1; m >>= 1) mx = fmaxf(mx, __shfl_xor(mx, m, 32));
  float e = expf(acc - mx);
  float se = e;
#pragma unroll
  for (int m = 16; m >= 1; m >>= 1) se += __shfl_xor(se, m, 32);
  float p = 0.99f * (e / se) + 3.125e-4f;
  float y = logf(p) + gum[(long)r * gs + c];
  float by = y; int bi = d;
#pragma unroll
  for (int m = 16; m >= 1; m >>= 1) {
    float oy = __shfl_xor(by, m, 32);
    int oi = __shfl_xor(bi, m, 32);
    if (oy > by || (oy == by && oi < bi)) { by = oy; bi = oi; }
  }
  float oh = (d == bi) ? 1.0f : 0.0f;
  float outv = (oh + p) - p;
  float* ob = out + (size_t)t * OUT_C + (size_t)r * OUT_RSTRIDE;
  if (which) {
    ob[c] = outv;
    ob[5120 + c] = acc;
    float fn = (t + 1 < T_STEPS) ? isf[r * T_STEPS + t + 1] : 0.0f;
    stoch_in[r * SD + c] = outv * (1.0f - fn) + init_stoch[r * SD + c] * fn;
    if (c < A_DIM) {
      float a = (t + 1 < T_STEPS) ? pa[(r * T_STEPS + t + 1) * A_DIM + c] : 0.0f;
      a = a * (1.0f / fmaxf(fabsf(a), 1.0f));
      a_eff[r * 8 + c] = a * (1.0f - fn);
    }
  } else {
    ob[6144 + c] = outv;
    ob[7168 + c] = acc;
  }
}

// ---------------- host ----------------
static inline GemmArgs mkargs(const float* A0, long sA0, int cA0,
                              const float* A1, long sA1,
                              const float* W, int N, int Ktot, int KS, int nsplit, float* P) {
  GemmArgs g; g.A0 = A0; g.sA0 = sA0; g.cA0 = cA0; g.A1 = A1; g.sA1 = sA1;
  g.W = W; g.N = N; g.Ktot = Ktot; g.KS = KS; g.nsplit = nsplit; g.P = P;
  return g;
}

extern "C" void kernel_launch(void* const* d_in, const int* in_sizes, int n_in,
                              void* d_out, int out_size, void* d_ws, size_t ws_size,
                              hipStream_t stream) {
  const float* embed  = (const float*)d_in[0];
  const float* pa     = (const float*)d_in[1];
  const float* isf    = (const float*)d_in[2];
  const float* gprior = (const float*)d_in[3];
  const float* gpost  = (const float*)d_in[4];
  const float* w_init = (const float*)d_in[5];
  const float* W1  = (const float*)d_in[6];
  const float* g1  = (const float*)d_in[7];
  const float* b1  = (const float*)d_in[8];
  const float* Wg  = (const float*)d_in[9];
  const float* gg  = (const float*)d_in[10];
  const float* bg  = (const float*)d_in[11];
  const float* W2a = (const float*)d_in[12];
  const float* g2  = (const float*)d_in[13];
  const float* b2  = (const float*)d_in[14];
  const float* W2b = (const float*)d_in[15];
  const float* bb2 = (const float*)d_in[16];
  const float* Wo  = (const float*)d_in[17];
  const float* go  = (const float*)d_in[18];
  const float* bo  = (const float*)d_in[19];
  const float* Wob = (const float*)d_in[20];
  const float* bbo = (const float*)d_in[21];
  float* out = (float*)d_out;
  float* ws  = (float*)d_ws;

  // workspace (floats): partial buffers aliased into the Pg arena
  // (lifetimes strictly sequential: Pimg1[s1-2] -> Pg[s3-4] -> Pa/Pb[s5-6] -> Ps0/Ps1[s7-8])
  float* Pg    = ws;                    // 20*16*12288 = 3,932,160
  float* Pimg1 = ws;                    // 278,528   (alias, dead before gruG)
  float* Pa    = ws + 278528;           // 524,288   (prior img2a partials)
  float* Pb    = ws + 802816;           // 524,288   (obs partials)
  float* Ps0   = ws + 1327104;          // 262,144   (prior sample partials)
  float* Ps1   = ws + 1589248;          // 262,144   (post sample partials)
  float* Sg    = ws + 3932160;          // 196,608
  float* red_s = Sg + 196608;           // 192
  float* red_q = red_s + 192;           // 192 (+pad)
  float* st_   = red_s + 512;
  float* init_stoch = st_;              // 16,384
  float* init_deter = st_ + 16384;      // 4,096
  float* stoch_in   = st_ + 20480;      // 16,384
  float* din0       = st_ + 36864;      // 65,536
  float* din1       = st_ + 102400;     // 65,536
  float* a_eff      = st_ + 167936;     // 128
  float* x          = st_ + 168064;     // 16,384
  float* h          = st_ + 184448;     // 16,384
  float* h2         = st_ + 200832;     // 16,384

  GemmArgs Z = mkargs(nullptr, 0, 0, nullptr, 0, nullptr, 1, 0, 64, 0, nullptr);

  // ---- OE precompute: e @ Wo[0:E] -> out post-logit slots (consumed in-loop, overwritten)
  k_mm<<<dim3(16, 16), 256, 0, stream>>>(embed, E_DIM, Wo, E_DIM, out + 5120, OUT_C);

  // ---- init: init_deter = tanh(w_init); init_stoch = st_mode(prior_logits(init_deter))
  k_tanh<<<4, 1024, 0, stream>>>(w_init, init_deter);
  k_gemm<true><<<dim3(2, 32, 1), 256, 0, stream>>>(
      mkargs(init_deter, 0, DET, nullptr, 0, W2a, HID, DET, 128, 32, Pb), Z);
  k_fin2<<<16, 1024, 0, stream>>>(Pb, 32, nullptr, 0, g2, b2, x,
                                  Pb, 32, nullptr, 0, g2, b2, x);
  k_gemm<true><<<dim3(2, 16, 1), 256, 0, stream>>>(
      mkargs(x, HID, HID, nullptr, 0, W2b, SD, HID, 64, 16, Ps1), Z);
  k_samp_init<<<16, 1024, 0, stream>>>(Ps1, 16, bb2, init_stoch);

  // ---- t=0 prep (f[:,0]==1 -> all init) ----
  k_prep<<<16, 256, 0, stream>>>(isf, pa, 0, init_stoch, init_deter, 0,
                                 init_stoch, init_deter, stoch_in, din0, a_eff);

  const float* Wo2 = Wo + (size_t)E_DIM * HID;
  for (int t = 0; t < T_STEPS; t++) {
    float* din_cur  = (t & 1) ? din1 : din0;
    float* din_next = (t & 1) ? din0 : din1;
    // 1) img1 GEMM: concat(stoch,a)[1030] @ W1 -> 1024 partials
    k_gemm<true><<<dim3(2, 17, 1), 256, 0, stream>>>(
        mkargs(stoch_in, SD, SD, a_eff, 8, W1, HID, SD + A_DIM, 64, 17, Pimg1), Z);
    // 2) img1 finish -> x
    k_fin2<<<16, 1024, 0, stream>>>(Pimg1, 17, nullptr, 0, g1, b1, x,
                                    Pimg1, 17, nullptr, 0, g1, b1, x);
    // 3) GRU GEMM: concat(x, deter_in)[5120] @ Wg -> 12288 partials (Wg L3-cacheable)
    k_gemm<false><<<dim3(24, 20, 1), 256, 0, stream>>>(
        mkargs(x, HID, HID, din_cur, DET, Wg, 3 * DET, HID + DET, 256, 20, Pg), Z);
    // 4) reduce partials -> Sg + per-chunk (sum, sumsq)
    k_red<<<dim3(12, 16), 256, 0, stream>>>(Pg, 20, Sg, red_s, red_q);
    // 5) obs + prior GEMMs with fused gate recompute (z=0 obs -> Pb, z=1 prior -> Pa)
    k_obsg2<<<dim3(2, 32, 2), 256, 0, stream>>>(Sg, red_s, red_q, gg, bg, din_cur, din_next,
                                                init_deter, isf, t, Wo2, Pb, W2a, Pa, out);
    // 6) batched finish: prior h (Pa) || obs h2 (Pb + OE)
    k_fin2<<<32, 1024, 0, stream>>>(Pa, 32, nullptr, 0, g2, b2, h,
                                    Pb, 32, out + (size_t)t * OUT_C + 5120, OUT_RSTRIDE,
                                    go, bo, h2);
    // 7) batched sample GEMMs: h@W2b -> Ps0 || h2@Wob -> Ps1
    k_gemm<true><<<dim3(2, 16, 2), 256, 0, stream>>>(
        mkargs(h, HID, HID, nullptr, 0, W2b, SD, HID, 64, 16, Ps0),
        mkargs(h2, HID, HID, nullptr, 0, Wob, SD, HID, 64, 16, Ps1));
    // 8) batched sample: prior || post (+ next-step blends)
    k_samp2<<<32, 1024, 0, stream>>>(
        Ps0, bb2, gprior + (size_t)t * SD, (long)T_STEPS * SD,
        Ps1, bbo, gpost + (size_t)t * SD, (long)T_STEPS * SD,
        out, t, 16, isf, pa, stoch_in, a_eff, init_stoch);
  }
}

// Round 12
// 10367.903 us; speedup vs baseline: 2.2751x; 1.0118x over previous
//
#include <hip/hip_runtime.h>
#include <cmath>

// RSSM scan: B=16, T=64, A=6, E=12288, DET=4096, HID=1024, S=32, D=32
// fp32 throughout (argmax stability). Deterministic fixed-order reductions.
// 8 launches/step. This round: k_gemm weight loads f2v -> f4v (16B/lane),
// 1024 cols/block. Everything else identical to round 11 (10.49 ms).

#define B 16
#define T_STEPS 64
#define A_DIM 6
#define E_DIM 12288
#define DET 4096
#define HID 1024
#define SD 1024
#define OUT_C 8192
#define OUT_RSTRIDE (T_STEPS * OUT_C)

typedef float f2v __attribute__((ext_vector_type(2)));
typedef float f4v __attribute__((ext_vector_type(4)));

#define NTL(p) __builtin_nontemporal_load(p)

// ---------------- block reduce (deterministic) ----------------
__device__ __forceinline__ float block_sum(float v, float* red, int nw) {
#pragma unroll
  for (int m = 32; m >= 1; m >>= 1) v += __shfl_xor(v, m, 64);
  int wid = threadIdx.x >> 6;
  if ((threadIdx.x & 63) == 0) red[wid] = v;
  __syncthreads();
  if (wid == 0) {
    float s = ((int)threadIdx.x < nw) ? red[threadIdx.x] : 0.0f;
#pragma unroll
    for (int m = 8; m >= 1; m >>= 1) s += __shfl_xor(s, m, 16);
    if (threadIdx.x == 0) red[0] = s;
  }
  __syncthreads();
  float out = red[0];
  __syncthreads();
  return out;
}

__global__ __launch_bounds__(1024) void k_tanh(const float* __restrict__ w, float* __restrict__ o) {
  int i = blockIdx.x * 1024 + threadIdx.x;
  if (i < DET) o[i] = tanhf(w[i]);
}

// ---------------- prep (t=0 only) ----------------
__global__ __launch_bounds__(256) void k_prep(
    const float* __restrict__ isf, const float* __restrict__ pa, int t,
    const float* __restrict__ stoch_prev,
    const float* __restrict__ deter_prev, long deter_prev_stride,
    const float* __restrict__ init_stoch, const float* __restrict__ init_deter_row,
    float* __restrict__ stoch_in, float* __restrict__ deter_in, float* __restrict__ a_eff) {
  int r = blockIdx.x;
  float f = isf[r * T_STEPS + t];
  float omf = 1.0f - f;
  for (int c = threadIdx.x; c < SD; c += 256)
    stoch_in[r * SD + c] = stoch_prev[r * SD + c] * omf + init_stoch[r * SD + c] * f;
  for (int c = threadIdx.x; c < DET; c += 256)
    deter_in[r * DET + c] = deter_prev[(long)r * deter_prev_stride + c] * omf + init_deter_row[c] * f;
  if ((int)threadIdx.x < A_DIM) {
    float a = pa[(r * T_STEPS + t) * A_DIM + threadIdx.x];
    a = a * (1.0f / fmaxf(fabsf(a), 1.0f));
    a_eff[r * 8 + threadIdx.x] = a * omf;
  }
}

// ---------------- K-split GEMM: P[split][16][N] partials (z-batched, f4v) ----------------
// 256 threads, 1024 cols/block (f4v, 16B/lane), 16 rows staged in LDS.
struct GemmArgs {
  const float* A0; long sA0; int cA0;
  const float* A1; long sA1;
  const float* W; int N; int Ktot; int KS; int nsplit;
  float* P;
};

template <bool NT>
__global__ __launch_bounds__(256) void k_gemm(GemmArgs ga, GemmArgs gb) {
  const GemmArgs g = blockIdx.z ? gb : ga;
  if ((int)blockIdx.y >= g.nsplit) return;
  const int tid = threadIdx.x;
  const int c0 = blockIdx.x * 1024 + tid * 4;
  const int k0 = (int)blockIdx.y * g.KS;
  __shared__ float in_s[16][64];
  float acc[16][4];
#pragma unroll
  for (int r = 0; r < 16; r++) { acc[r][0] = 0.f; acc[r][1] = 0.f; acc[r][2] = 0.f; acc[r][3] = 0.f; }
  for (int kb = 0; kb < g.KS; kb += 64) {
    const int kbase = k0 + kb;
#pragma unroll
    for (int j = 0; j < 4; j++) {
      int ii = tid + j * 256;
      int r = ii >> 6, kk = ii & 63;
      int k = kbase + kk;
      float v = 0.f;
      if (k < g.cA0) v = g.A0[(long)r * g.sA0 + k];
      else if (k < g.Ktot) v = g.A1[(long)r * g.sA1 + (k - g.cA0)];
      in_s[r][kk] = v;
    }
    __syncthreads();
    if (kbase + 64 <= g.Ktot) {
      const float* wp = g.W + (size_t)kbase * g.N + c0;
#pragma unroll 4
      for (int kk = 0; kk < 64; kk++) {
        f4v w = NT ? NTL((const f4v*)wp) : *(const f4v*)wp;
        wp += g.N;
#pragma unroll
        for (int r = 0; r < 16; r++) {
          float iv = in_s[r][kk];
          acc[r][0] += iv * w[0]; acc[r][1] += iv * w[1];
          acc[r][2] += iv * w[2]; acc[r][3] += iv * w[3];
        }
      }
    } else {  // K tail (img1: Ktot=1030)
#pragma unroll 4
      for (int kk = 0; kk < 64; kk++) {
        int krow = kbase + kk; if (krow >= g.Ktot) krow = g.Ktot - 1;
        const f4v w = *(const f4v*)(g.W + (size_t)krow * g.N + c0);
#pragma unroll
        for (int r = 0; r < 16; r++) {
          float iv = in_s[r][kk];
          acc[r][0] += iv * w[0]; acc[r][1] += iv * w[1];
          acc[r][2] += iv * w[2]; acc[r][3] += iv * w[3];
        }
      }
    }
    __syncthreads();
  }
#pragma unroll
  for (int r = 0; r < 16; r++)
    *(f4v*)(g.P + ((size_t)blockIdx.y * 16 + r) * g.N + c0) =
        f4v{acc[r][0], acc[r][1], acc[r][2], acc[r][3]};
}

// ---------------- batched finish: (optional add) + sum partials + LN + silu ----------
__global__ __launch_bounds__(1024) void k_fin2(
    const float* __restrict__ Pa_, int nPa, const float* __restrict__ addA, long adsA,
    const float* __restrict__ gva, const float* __restrict__ bva, float* __restrict__ oa,
    const float* __restrict__ Pb_, int nPb, const float* __restrict__ addB, long adsB,
    const float* __restrict__ gvb, const float* __restrict__ bvb, float* __restrict__ ob) {
  int which = blockIdx.x >> 4, r = blockIdx.x & 15, c = threadIdx.x;
  const float* P = which ? Pb_ : Pa_;
  int nP = which ? nPb : nPa;
  const float* add = which ? addB : addA;
  long ads = which ? adsB : adsA;
  const float* gv = which ? gvb : gva;
  const float* bv = which ? bvb : bva;
  float* o = which ? ob : oa;
  __shared__ float red[18];
  float v = add ? add[(size_t)r * ads + c] : 0.0f;
  for (int ks = 0; ks < nP; ks++) v += P[((size_t)ks * 16 + r) * HID + c];
  float m = block_sum(v, red, 16) * (1.0f / (float)HID);
  float d = v - m;
  float var = block_sum(d * d, red, 16) * (1.0f / (float)HID);
  float rs = 1.0f / sqrtf(var + 1e-3f);
  float y = d * rs * gv[c] + bv[c];
  float s = 1.0f / (1.0f + expf(-y));
  o[r * HID + c] = y * s;
}

// ---------------- init sample (mode) ----------------
__global__ __launch_bounds__(1024) void k_samp_init(
    const float* __restrict__ P, int nP, const float* __restrict__ bb,
    float* __restrict__ st) {
  int r = blockIdx.x, c = threadIdx.x;
  float acc = bb[c];
  for (int ks = 0; ks < nP; ks++) acc += P[((size_t)ks * 16 + r) * SD + c];
  int d = c & 31;
  float mx = acc;
#pragma unroll
  for (int m = 16; m >= 1; m >>= 1) mx = fmaxf(mx, __shfl_xor(mx, m, 32));
  float e = expf(acc - mx);
  float se = e;
#pragma unroll
  for (int m = 16; m >= 1; m >>= 1) se += __shfl_xor(se, m, 32);
  float p = 0.99f * (e / se) + 3.125e-4f;
  float by = p; int bi = d;
#pragma unroll
  for (int m = 16; m >= 1; m >>= 1) {
    float oy = __shfl_xor(by, m, 32);
    int oi = __shfl_xor(bi, m, 32);
    if (oy > by || (oy == by && oi < bi)) { by = oy; bi = oi; }
  }
  float oh = (d == bi) ? 1.0f : 0.0f;
  st[r * SD + c] = (oh + p) - p;
}

// ---------------- tiled GEMM (OE precompute): out[M x 1024] = A @ Bw ----------
__global__ __launch_bounds__(256) void k_mm(const float* __restrict__ A, long lda,
                                            const float* __restrict__ Bw, int K,
                                            float* __restrict__ out, long ldo) {
  __shared__ float As[32][68];
  __shared__ float Bs[32][68];
  const int tid = threadIdx.x;
  const int tx = tid & 15, ty = tid >> 4;
  const int row0 = blockIdx.y * 64, col0 = blockIdx.x * 64;
  const int ar = tid >> 2, ak = (tid & 3) * 8;
  const int bk = tid >> 4, bc = (tid & 15) * 4;
  float acc[4][4] = {};
  const float* ap = A + (size_t)(row0 + ar) * lda + ak;
  const float* bp = Bw + (size_t)bk * HID + col0 + bc;
  for (int k0 = 0; k0 < K; k0 += 32) {
    float4 a0 = *(const float4*)(ap + k0);
    float4 a1 = *(const float4*)(ap + k0 + 4);
    float4 b0 = *(const float4*)(bp + (size_t)k0 * HID);
    float4 b1 = *(const float4*)(bp + (size_t)(k0 + 16) * HID);
    __syncthreads();
    As[ak + 0][ar] = a0.x; As[ak + 1][ar] = a0.y; As[ak + 2][ar] = a0.z; As[ak + 3][ar] = a0.w;
    As[ak + 4][ar] = a1.x; As[ak + 5][ar] = a1.y; As[ak + 6][ar] = a1.z; As[ak + 7][ar] = a1.w;
    *(float4*)&Bs[bk][bc] = b0;
    *(float4*)&Bs[bk + 16][bc] = b1;
    __syncthreads();
#pragma unroll
    for (int kk = 0; kk < 32; kk++) {
      float4 av = *(const float4*)&As[kk][ty * 4];
      float4 bv = *(const float4*)&Bs[kk][tx * 4];
      acc[0][0] += av.x * bv.x; acc[0][1] += av.x * bv.y; acc[0][2] += av.x * bv.z; acc[0][3] += av.x * bv.w;
      acc[1][0] += av.y * bv.x; acc[1][1] += av.y * bv.y; acc[1][2] += av.y * bv.z; acc[1][3] += av.y * bv.w;
      acc[2][0] += av.z * bv.x; acc[2][1] += av.z * bv.y; acc[2][2] += av.z * bv.z; acc[2][3] += av.z * bv.w;
      acc[3][0] += av.w * bv.x; acc[3][1] += av.w * bv.y; acc[3][2] += av.w * bv.z; acc[3][3] += av.w * bv.w;
    }
  }
#pragma unroll
  for (int i = 0; i < 4; i++) {
    int col = col0 + tx * 4;
    float4 o;
    o.x = acc[i][0]; o.y = acc[i][1]; o.z = acc[i][2]; o.w = acc[i][3];
    *(float4*)(out + (size_t)(row0 + ty * 4 + i) * ldo + col) = o;
  }
}

// ---------------- GRU stage-1 reduce: sum splits + (sum, sumsq) per chunk ----------
__global__ __launch_bounds__(256) void k_red(const float* __restrict__ P, int nP,
                                             float* __restrict__ S,
                                             float* __restrict__ red_s, float* __restrict__ red_q) {
  int chunk = blockIdx.x, r = blockIdx.y;
  int c = chunk * 1024 + threadIdx.x * 4;
  float4 s = {0, 0, 0, 0};
  for (int ks = 0; ks < nP; ks++) {
    float4 v = *(const float4*)(P + ((size_t)ks * 16 + r) * (3 * DET) + c);
    s.x += v.x; s.y += v.y; s.z += v.z; s.w += v.w;
  }
  *(float4*)(S + (size_t)r * (3 * DET) + c) = s;
  float sx = (s.x + s.y) + (s.z + s.w);
  float sq = (s.x * s.x + s.y * s.y) + (s.z * s.z + s.w * s.w);
  __shared__ float rbuf[8];
#pragma unroll
  for (int m = 32; m >= 1; m >>= 1) { sx += __shfl_xor(sx, m, 64); sq += __shfl_xor(sq, m, 64); }
  int wid = threadIdx.x >> 6;
  if ((threadIdx.x & 63) == 0) { rbuf[wid] = sx; rbuf[4 + wid] = sq; }
  __syncthreads();
  if (threadIdx.x == 0) {
    red_s[r * 12 + chunk] = (rbuf[0] + rbuf[1]) + (rbuf[2] + rbuf[3]);
    red_q[r * 12 + chunk] = (rbuf[4] + rbuf[5]) + (rbuf[6] + rbuf[7]);
  }
}

// ---- obs+prior GEMM with fused GRU-gate recompute (z-batched, per 128-col K-slice) ----
// z=0: obs (W=Wo2 -> Pb); z=1: prior (W=W2a -> Pa). z0/tile0 writes deter + din_next.
__global__ __launch_bounds__(256) void k_obsg2(
    const float* __restrict__ Sg, const float* __restrict__ red_s, const float* __restrict__ red_q,
    const float* __restrict__ gg, const float* __restrict__ bg,
    const float* __restrict__ din_cur, float* __restrict__ din_next,
    const float* __restrict__ init_deter, const float* __restrict__ isf, int t,
    const float* __restrict__ W0, float* __restrict__ P0,
    const float* __restrict__ W1p, float* __restrict__ P1p,
    float* __restrict__ out) {
  const int tid = threadIdx.x;
  const int tile = blockIdx.x;       // 0..1 (col half)
  const int split = blockIdx.y;      // 0..31 (K slice of 128)
  const int z = blockIdx.z;
  const float* W = z ? W1p : W0;
  float* P = z ? P1p : P0;
  const int c0 = tile * 512 + tid * 2;
  const int j0 = split * 128;
  __shared__ float dn_s[16][128];
  __shared__ float mvf[16][3];
  if (tid < 16) {
    int r = tid;
    float s = 0.f, q = 0.f;
    for (int k2 = 0; k2 < 12; k2++) { s += red_s[r * 12 + k2]; q += red_q[r * 12 + k2]; }
    float m = s * (1.0f / (float)(3 * DET));
    float var = q * (1.0f / (float)(3 * DET)) - m * m;
    mvf[r][0] = m; mvf[r][1] = 1.0f / sqrtf(var + 1e-3f);
    mvf[r][2] = (t + 1 < T_STEPS) ? isf[r * T_STEPS + t + 1] : 0.0f;
  }
  __syncthreads();
  for (int e = tid; e < 16 * 128; e += 256) {
    int r = e >> 7, jj = e & 127;
    int j = j0 + jj;
    float m = mvf[r][0], rs = mvf[r][1];
    const float* Sr = Sg + (size_t)r * (3 * DET);
    float lr = (Sr[j] - m) * rs * gg[j] + bg[j];
    float lc = (Sr[j + DET] - m) * rs * gg[j + DET] + bg[j + DET];
    float lu = (Sr[j + 2 * DET] - m) * rs * gg[j + 2 * DET] + bg[j + 2 * DET];
    float rr = 1.0f / (1.0f + expf(-lr));
    float cd = tanhf(rr * lc);
    float uu = 1.0f / (1.0f + expf(-(lu - 1.0f)));
    float dn = uu * cd + (1.0f - uu) * din_cur[r * DET + j];
    dn_s[r][jj] = dn;
    if (z == 0 && tile == 0) {
      out[(size_t)(r * T_STEPS + t) * OUT_C + 1024 + j] = dn;
      float ft = mvf[r][2];
      din_next[r * DET + j] = dn * (1.0f - ft) + init_deter[j] * ft;
    }
  }
  __syncthreads();
  float acc[16][2];
#pragma unroll
  for (int r = 0; r < 16; r++) { acc[r][0] = 0.f; acc[r][1] = 0.f; }
  for (int kb = 0; kb < 128; kb += 64) {
    const float* wp = W + (size_t)(j0 + kb) * HID + c0;
#pragma unroll 4
    for (int kk = 0; kk < 64; kk++) {
      f2v w = NTL((const f2v*)wp);
      wp += HID;
#pragma unroll
      for (int r = 0; r < 16; r++) {
        float iv = dn_s[r][kb + kk];
        acc[r][0] += iv * w[0]; acc[r][1] += iv * w[1];
      }
    }
  }
#pragma unroll
  for (int r = 0; r < 16; r++)
    *(f2v*)(P + ((size_t)split * 16 + r) * HID + c0) = f2v{acc[r][0], acc[r][1]};
}

// ---------------- batched sample: prior (which=0) + post (which=1, blends) ----------
__global__ __launch_bounds__(1024) void k_samp2(
    const float* __restrict__ P0, const float* __restrict__ bb0,
    const float* __restrict__ gum0, long gs0,
    const float* __restrict__ P1, const float* __restrict__ bb1,
    const float* __restrict__ gum1, long gs1,
    float* __restrict__ out, int t, int nP,
    const float* __restrict__ isf, const float* __restrict__ pa,
    float* __restrict__ stoch_in, float* __restrict__ a_eff,
    const float* __restrict__ init_stoch) {
  int which = blockIdx.x >> 4, r = blockIdx.x & 15, c = threadIdx.x;
  const float* P = which ? P1 : P0;
  const float* bbv = which ? bb1 : bb0;
  const float* gum = which ? gum1 : gum0;
  long gs = which ? gs1 : gs0;
  float acc = bbv[c];
  for (int ks = 0; ks < nP; ks++) acc += P[((size_t)ks * 16 + r) * SD + c];
  int d = c & 31;
  float mx = acc;
#pragma unroll
  for (int m = 16; m >= 1; m >>= 1) mx = fmaxf(mx, __shfl_xor(mx, m, 32));
  float e = expf(acc - mx);
  float se = e;
#pragma unroll
  for (int m = 16; m >= 1; m >>= 1) se += __shfl_xor(se, m, 32);
  float p = 0.99f * (e / se) + 3.125e-4f;
  float y = logf(p) + gum[(long)r * gs + c];
  float by = y; int bi = d;
#pragma unroll
  for (int m = 16; m >= 1; m >>= 1) {
    float oy = __shfl_xor(by, m, 32);
    int oi = __shfl_xor(bi, m, 32);
    if (oy > by || (oy == by && oi < bi)) { by = oy; bi = oi; }
  }
  float oh = (d == bi) ? 1.0f : 0.0f;
  float outv = (oh + p) - p;
  float* ob = out + (size_t)t * OUT_C + (size_t)r * OUT_RSTRIDE;
  if (which) {
    ob[c] = outv;
    ob[5120 + c] = acc;
    float fn = (t + 1 < T_STEPS) ? isf[r * T_STEPS + t + 1] : 0.0f;
    stoch_in[r * SD + c] = outv * (1.0f - fn) + init_stoch[r * SD + c] * fn;
    if (c < A_DIM) {
      float a = (t + 1 < T_STEPS) ? pa[(r * T_STEPS + t + 1) * A_DIM + c] : 0.0f;
      a = a * (1.0f / fmaxf(fabsf(a), 1.0f));
      a_eff[r * 8 + c] = a * (1.0f - fn);
    }
  } else {
    ob[6144 + c] = outv;
    ob[7168 + c] = acc;
  }
}

// ---------------- host ----------------
static inline GemmArgs mkargs(const float* A0, long sA0, int cA0,
                              const float* A1, long sA1,
                              const float* W, int N, int Ktot, int KS, int nsplit, float* P) {
  GemmArgs g; g.A0 = A0; g.sA0 = sA0; g.cA0 = cA0; g.A1 = A1; g.sA1 = sA1;
  g.W = W; g.N = N; g.Ktot = Ktot; g.KS = KS; g.nsplit = nsplit; g.P = P;
  return g;
}

extern "C" void kernel_launch(void* const* d_in, const int* in_sizes, int n_in,
                              void* d_out, int out_size, void* d_ws, size_t ws_size,
                              hipStream_t stream) {
  const float* embed  = (const float*)d_in[0];
  const float* pa     = (const float*)d_in[1];
  const float* isf    = (const float*)d_in[2];
  const float* gprior = (const float*)d_in[3];
  const float* gpost  = (const float*)d_in[4];
  const float* w_init = (const float*)d_in[5];
  const float* W1  = (const float*)d_in[6];
  const float* g1  = (const float*)d_in[7];
  const float* b1  = (const float*)d_in[8];
  const float* Wg  = (const float*)d_in[9];
  const float* gg  = (const float*)d_in[10];
  const float* bg  = (const float*)d_in[11];
  const float* W2a = (const float*)d_in[12];
  const float* g2  = (const float*)d_in[13];
  const float* b2  = (const float*)d_in[14];
  const float* W2b = (const float*)d_in[15];
  const float* bb2 = (const float*)d_in[16];
  const float* Wo  = (const float*)d_in[17];
  const float* go  = (const float*)d_in[18];
  const float* bo  = (const float*)d_in[19];
  const float* Wob = (const float*)d_in[20];
  const float* bbo = (const float*)d_in[21];
  float* out = (float*)d_out;
  float* ws  = (float*)d_ws;

  // workspace (floats): partial buffers aliased into the Pg arena
  float* Pg    = ws;                    // 20*16*12288 = 3,932,160
  float* Pimg1 = ws;                    // 278,528   (alias, dead before gruG)
  float* Pa    = ws + 278528;           // 524,288   (prior img2a partials)
  float* Pb    = ws + 802816;           // 524,288   (obs partials)
  float* Ps0   = ws + 1327104;          // 262,144   (prior sample partials)
  float* Ps1   = ws + 1589248;          // 262,144   (post sample partials)
  float* Sg    = ws + 3932160;          // 196,608
  float* red_s = Sg + 196608;           // 192
  float* red_q = red_s + 192;           // 192 (+pad)
  float* st_   = red_s + 512;
  float* init_stoch = st_;              // 16,384
  float* init_deter = st_ + 16384;      // 4,096
  float* stoch_in   = st_ + 20480;      // 16,384
  float* din0       = st_ + 36864;      // 65,536
  float* din1       = st_ + 102400;     // 65,536
  float* a_eff      = st_ + 167936;     // 128
  float* x          = st_ + 168064;     // 16,384
  float* h          = st_ + 184448;     // 16,384
  float* h2         = st_ + 200832;     // 16,384

  GemmArgs Z = mkargs(nullptr, 0, 0, nullptr, 0, nullptr, 1, 0, 64, 0, nullptr);

  // ---- OE precompute: e @ Wo[0:E] -> out post-logit slots (consumed in-loop, overwritten)
  k_mm<<<dim3(16, 16), 256, 0, stream>>>(embed, E_DIM, Wo, E_DIM, out + 5120, OUT_C);

  // ---- init: init_deter = tanh(w_init); init_stoch = st_mode(prior_logits(init_deter))
  k_tanh<<<4, 1024, 0, stream>>>(w_init, init_deter);
  k_gemm<true><<<dim3(1, 32, 1), 256, 0, stream>>>(
      mkargs(init_deter, 0, DET, nullptr, 0, W2a, HID, DET, 128, 32, Pb), Z);
  k_fin2<<<16, 1024, 0, stream>>>(Pb, 32, nullptr, 0, g2, b2, x,
                                  Pb, 32, nullptr, 0, g2, b2, x);
  k_gemm<true><<<dim3(1, 16, 1), 256, 0, stream>>>(
      mkargs(x, HID, HID, nullptr, 0, W2b, SD, HID, 64, 16, Ps1), Z);
  k_samp_init<<<16, 1024, 0, stream>>>(Ps1, 16, bb2, init_stoch);

  // ---- t=0 prep (f[:,0]==1 -> all init) ----
  k_prep<<<16, 256, 0, stream>>>(isf, pa, 0, init_stoch, init_deter, 0,
                                 init_stoch, init_deter, stoch_in, din0, a_eff);

  const float* Wo2 = Wo + (size_t)E_DIM * HID;
  for (int t = 0; t < T_STEPS; t++) {
    float* din_cur  = (t & 1) ? din1 : din0;
    float* din_next = (t & 1) ? din0 : din1;
    // 1) img1 GEMM: concat(stoch,a)[1030] @ W1 -> 1024 partials
    k_gemm<true><<<dim3(1, 17, 1), 256, 0, stream>>>(
        mkargs(stoch_in, SD, SD, a_eff, 8, W1, HID, SD + A_DIM, 64, 17, Pimg1), Z);
    // 2) img1 finish -> x
    k_fin2<<<16, 1024, 0, stream>>>(Pimg1, 17, nullptr, 0, g1, b1, x,
                                    Pimg1, 17, nullptr, 0, g1, b1, x);
    // 3) GRU GEMM: concat(x, deter_in)[5120] @ Wg -> 12288 partials (Wg L3-cacheable)
    k_gemm<false><<<dim3(12, 20, 1), 256, 0, stream>>>(
        mkargs(x, HID, HID, din_cur, DET, Wg, 3 * DET, HID + DET, 256, 20, Pg), Z);
    // 4) reduce partials -> Sg + per-chunk (sum, sumsq)
    k_red<<<dim3(12, 16), 256, 0, stream>>>(Pg, 20, Sg, red_s, red_q);
    // 5) obs + prior GEMMs with fused gate recompute (z=0 obs -> Pb, z=1 prior -> Pa)
    k_obsg2<<<dim3(2, 32, 2), 256, 0, stream>>>(Sg, red_s, red_q, gg, bg, din_cur, din_next,
                                                init_deter, isf, t, Wo2, Pb, W2a, Pa, out);
    // 6) batched finish: prior h (Pa) || obs h2 (Pb + OE)
    k_fin2<<<32, 1024, 0, stream>>>(Pa, 32, nullptr, 0, g2, b2, h,
                                    Pb, 32, out + (size_t)t * OUT_C + 5120, OUT_RSTRIDE,
                                    go, bo, h2);
    // 7) batched sample GEMMs: h@W2b -> Ps0 || h2@Wob -> Ps1
    k_gemm<true><<<dim3(1, 16, 2), 256, 0, stream>>>(
        mkargs(h, HID, HID, nullptr, 0, W2b, SD, HID, 64, 16, Ps0),
        mkargs(h2, HID, HID, nullptr, 0, Wob, SD, HID, 64, 16, Ps1));
    // 8) batched sample: prior || post (+ next-step blends)
    k_samp2<<<32, 1024, 0, stream>>>(
        Ps0, bb2, gprior + (size_t)t * SD, (long)T_STEPS * SD,
        Ps1, bbo, gpost + (size_t)t * SD, (long)T_STEPS * SD,
        out, t, 16, isf, pa, stoch_in, a_eff, init_stoch);
  }
}

// Round 14
// 10134.677 us; speedup vs baseline: 2.3274x; 1.0230x over previous
//
#include <hip/hip_runtime.h>
#include <cmath>

// RSSM scan: B=16, T=64, A=6, E=12288, DET=4096, HID=1024, S=32, D=32
// fp32 throughout (argmax stability). Deterministic fixed-order reductions.
// 7 launches/step: img1s (GEMM + prev-step post/prior sample recompute, fused),
// img1F, gruG, red, obsg2 (gate fused, z-batched), fin2, sampG.
// Epilogue: k_samp2 for t=63. NT policy: NT only non-Wg weight streams.

#define B 16
#define T_STEPS 64
#define A_DIM 6
#define E_DIM 12288
#define DET 4096
#define HID 1024
#define SD 1024
#define OUT_C 8192
#define OUT_RSTRIDE (T_STEPS * OUT_C)

typedef float f2v __attribute__((ext_vector_type(2)));
typedef float f4v __attribute__((ext_vector_type(4)));

#define NTL(p) __builtin_nontemporal_load(p)

// ---------------- block reduce (deterministic) ----------------
__device__ __forceinline__ float block_sum(float v, float* red, int nw) {
#pragma unroll
  for (int m = 32; m >= 1; m >>= 1) v += __shfl_xor(v, m, 64);
  int wid = threadIdx.x >> 6;
  if ((threadIdx.x & 63) == 0) red[wid] = v;
  __syncthreads();
  if (wid == 0) {
    float s = ((int)threadIdx.x < nw) ? red[threadIdx.x] : 0.0f;
#pragma unroll
    for (int m = 8; m >= 1; m >>= 1) s += __shfl_xor(s, m, 16);
    if (threadIdx.x == 0) red[0] = s;
  }
  __syncthreads();
  float out = red[0];
  __syncthreads();
  return out;
}

__global__ __launch_bounds__(1024) void k_tanh(const float* __restrict__ w, float* __restrict__ o) {
  int i = blockIdx.x * 1024 + threadIdx.x;
  if (i < DET) o[i] = tanhf(w[i]);
}

// ---------------- prep (t=0 only) ----------------
__global__ __launch_bounds__(256) void k_prep(
    const float* __restrict__ isf, const float* __restrict__ pa, int t,
    const float* __restrict__ stoch_prev,
    const float* __restrict__ deter_prev, long deter_prev_stride,
    const float* __restrict__ init_stoch, const float* __restrict__ init_deter_row,
    float* __restrict__ stoch_in, float* __restrict__ deter_in, float* __restrict__ a_eff) {
  int r = blockIdx.x;
  float f = isf[r * T_STEPS + t];
  float omf = 1.0f - f;
  for (int c = threadIdx.x; c < SD; c += 256)
    stoch_in[r * SD + c] = stoch_prev[r * SD + c] * omf + init_stoch[r * SD + c] * f;
  for (int c = threadIdx.x; c < DET; c += 256)
    deter_in[r * DET + c] = deter_prev[(long)r * deter_prev_stride + c] * omf + init_deter_row[c] * f;
  if ((int)threadIdx.x < A_DIM) {
    float a = pa[(r * T_STEPS + t) * A_DIM + threadIdx.x];
    a = a * (1.0f / fmaxf(fabsf(a), 1.0f));
    a_eff[r * 8 + threadIdx.x] = a * omf;
  }
}

// ---------------- K-split GEMM: P[split][16][N] partials (z-batched, f4v) ----------------
struct GemmArgs {
  const float* A0; long sA0; int cA0;
  const float* A1; long sA1;
  const float* W; int N; int Ktot; int KS; int nsplit;
  float* P;
};

template <bool NT>
__global__ __launch_bounds__(256) void k_gemm(GemmArgs ga, GemmArgs gb) {
  const GemmArgs g = blockIdx.z ? gb : ga;
  if ((int)blockIdx.y >= g.nsplit) return;
  const int tid = threadIdx.x;
  const int c0 = blockIdx.x * 1024 + tid * 4;
  const int k0 = (int)blockIdx.y * g.KS;
  __shared__ float in_s[16][64];
  float acc[16][4];
#pragma unroll
  for (int r = 0; r < 16; r++) { acc[r][0] = 0.f; acc[r][1] = 0.f; acc[r][2] = 0.f; acc[r][3] = 0.f; }
  for (int kb = 0; kb < g.KS; kb += 64) {
    const int kbase = k0 + kb;
#pragma unroll
    for (int j = 0; j < 4; j++) {
      int ii = tid + j * 256;
      int r = ii >> 6, kk = ii & 63;
      int k = kbase + kk;
      float v = 0.f;
      if (k < g.cA0) v = g.A0[(long)r * g.sA0 + k];
      else if (k < g.Ktot) v = g.A1[(long)r * g.sA1 + (k - g.cA0)];
      in_s[r][kk] = v;
    }
    __syncthreads();
    if (kbase + 64 <= g.Ktot) {
      const float* wp = g.W + (size_t)kbase * g.N + c0;
#pragma unroll 4
      for (int kk = 0; kk < 64; kk++) {
        f4v w = NT ? NTL((const f4v*)wp) : *(const f4v*)wp;
        wp += g.N;
#pragma unroll
        for (int r = 0; r < 16; r++) {
          float iv = in_s[r][kk];
          acc[r][0] += iv * w[0]; acc[r][1] += iv * w[1];
          acc[r][2] += iv * w[2]; acc[r][3] += iv * w[3];
        }
      }
    } else {
#pragma unroll 4
      for (int kk = 0; kk < 64; kk++) {
        int krow = kbase + kk; if (krow >= g.Ktot) krow = g.Ktot - 1;
        const f4v w = *(const f4v*)(g.W + (size_t)krow * g.N + c0);
#pragma unroll
        for (int r = 0; r < 16; r++) {
          float iv = in_s[r][kk];
          acc[r][0] += iv * w[0]; acc[r][1] += iv * w[1];
          acc[r][2] += iv * w[2]; acc[r][3] += iv * w[3];
        }
      }
    }
    __syncthreads();
  }
#pragma unroll
  for (int r = 0; r < 16; r++)
    *(f4v*)(g.P + ((size_t)blockIdx.y * 16 + r) * g.N + c0) =
        f4v{acc[r][0], acc[r][1], acc[r][2], acc[r][3]};
}

// ---- img1 GEMM fused with prev-step sample recompute ----
// by 0..16: img1 K-split blocks. For tprev>=0, by<16 recomputes the post-sample
// for its own 64-col slice (2 whole softmax groups) from Ps1, writes d_out,
// and stages the blended stoch directly into LDS. by==16 computes a_eff inline.
// by 17..32: prior-sample rows (r = by-17), write d_out only.
__global__ __launch_bounds__(256) void k_img1s(
    const float* __restrict__ stoch_in, const float* __restrict__ a_eff_g,
    const float* __restrict__ Ps1, const float* __restrict__ Ps0,
    const float* __restrict__ bbo, const float* __restrict__ bb2,
    const float* __restrict__ gpost_t, const float* __restrict__ gprior_t,
    float* __restrict__ out, int tprev,
    const float* __restrict__ isf, const float* __restrict__ pa, int t,
    const float* __restrict__ init_stoch,
    const float* __restrict__ W, float* __restrict__ P) {
  const int tid = threadIdx.x;
  const int by = blockIdx.y;
  if (by >= 17) {
    if (tprev < 0) return;
    int r = by - 17;
#pragma unroll
    for (int pass = 0; pass < 4; pass++) {
      int c = pass * 256 + tid;
      float acc = bb2[c];
      for (int ks = 0; ks < 16; ks++) acc += Ps0[((size_t)ks * 16 + r) * SD + c];
      int d = c & 31;
      float mx = acc;
#pragma unroll
      for (int m = 16; m >= 1; m >>= 1) mx = fmaxf(mx, __shfl_xor(mx, m, 32));
      float e = expf(acc - mx);
      float se = e;
#pragma unroll
      for (int m = 16; m >= 1; m >>= 1) se += __shfl_xor(se, m, 32);
      float p = 0.99f * (e / se) + 3.125e-4f;
      float y = logf(p) + gprior_t[(size_t)r * (T_STEPS * SD) + c];
      float by_ = y; int bi = d;
#pragma unroll
      for (int m = 16; m >= 1; m >>= 1) {
        float oy = __shfl_xor(by_, m, 32);
        int oi = __shfl_xor(bi, m, 32);
        if (oy > by_ || (oy == by_ && oi < bi)) { by_ = oy; bi = oi; }
      }
      float oh = (d == bi) ? 1.0f : 0.0f;
      float outv = (oh + p) - p;
      float* ob = out + (size_t)(r * T_STEPS + tprev) * OUT_C;
      ob[6144 + c] = outv;
      ob[7168 + c] = acc;
    }
    return;
  }
  __shared__ float in_s[16][64];
  const int kbase = by * 64;
  if (tprev >= 0) {
    if (by < 16) {
#pragma unroll
      for (int pass = 0; pass < 4; pass++) {
        int idx = pass * 256 + tid;
        int row = idx >> 6, col = idx & 63;
        int c = kbase + col;
        float acc = bbo[c];
        for (int ks = 0; ks < 16; ks++) acc += Ps1[((size_t)ks * 16 + row) * SD + c];
        int d = c & 31;
        float mx = acc;
#pragma unroll
        for (int m = 16; m >= 1; m >>= 1) mx = fmaxf(mx, __shfl_xor(mx, m, 32));
        float e = expf(acc - mx);
        float se = e;
#pragma unroll
        for (int m = 16; m >= 1; m >>= 1) se += __shfl_xor(se, m, 32);
        float p = 0.99f * (e / se) + 3.125e-4f;
        float y = logf(p) + gpost_t[(size_t)row * (T_STEPS * SD) + c];
        float by_ = y; int bi = d;
#pragma unroll
        for (int m = 16; m >= 1; m >>= 1) {
          float oy = __shfl_xor(by_, m, 32);
          int oi = __shfl_xor(bi, m, 32);
          if (oy > by_ || (oy == by_ && oi < bi)) { by_ = oy; bi = oi; }
        }
        float oh = (d == bi) ? 1.0f : 0.0f;
        float outv = (oh + p) - p;
        float* ob = out + (size_t)(row * T_STEPS + tprev) * OUT_C;
        ob[c] = outv;
        ob[5120 + c] = acc;
        float fn = isf[row * T_STEPS + t];
        in_s[row][col] = outv * (1.0f - fn) + init_stoch[(size_t)row * SD + c] * fn;
      }
    } else {  // by == 16: action slice (K 1024..1029)
      for (int e = tid; e < 16 * 64; e += 256) {
        int row = e >> 6, col = e & 63;
        float v = 0.f;
        if (col < A_DIM) {
          float a = pa[(row * T_STEPS + t) * A_DIM + col];
          a = a * (1.0f / fmaxf(fabsf(a), 1.0f));
          v = a * (1.0f - isf[row * T_STEPS + t]);
        }
        in_s[row][col] = v;
      }
    }
  } else {  // t == 0: stage from k_prep-initialized globals
    for (int e = tid; e < 16 * 64; e += 256) {
      int row = e >> 6, col = e & 63;
      int k = kbase + col;
      float v = 0.f;
      if (k < SD) v = stoch_in[row * SD + k];
      else if (k < SD + A_DIM) v = a_eff_g[row * 8 + (k - SD)];
      in_s[row][col] = v;
    }
  }
  __syncthreads();
  const int c0 = tid * 4;
  float acc4[16][4];
#pragma unroll
  for (int r = 0; r < 16; r++) { acc4[r][0] = 0.f; acc4[r][1] = 0.f; acc4[r][2] = 0.f; acc4[r][3] = 0.f; }
  if (kbase + 64 <= SD + A_DIM) {
    const float* wp = W + (size_t)kbase * HID + c0;
#pragma unroll 4
    for (int kk = 0; kk < 64; kk++) {
      f4v w = NTL((const f4v*)wp);
      wp += HID;
#pragma unroll
      for (int r = 0; r < 16; r++) {
        float iv = in_s[r][kk];
        acc4[r][0] += iv * w[0]; acc4[r][1] += iv * w[1];
        acc4[r][2] += iv * w[2]; acc4[r][3] += iv * w[3];
      }
    }
  } else {
#pragma unroll 4
    for (int kk = 0; kk < 64; kk++) {
      int krow = kbase + kk; if (krow >= SD + A_DIM) krow = SD + A_DIM - 1;
      const f4v w = *(const f4v*)(W + (size_t)krow * HID + c0);
#pragma unroll
      for (int r = 0; r < 16; r++) {
        float iv = in_s[r][kk];
        acc4[r][0] += iv * w[0]; acc4[r][1] += iv * w[1];
        acc4[r][2] += iv * w[2]; acc4[r][3] += iv * w[3];
      }
    }
  }
#pragma unroll
  for (int r = 0; r < 16; r++)
    *(f4v*)(P + ((size_t)by * 16 + r) * HID + c0) =
        f4v{acc4[r][0], acc4[r][1], acc4[r][2], acc4[r][3]};
}

// ---------------- batched finish: (optional add) + sum partials + LN + silu ----------
__global__ __launch_bounds__(1024) void k_fin2(
    const float* __restrict__ Pa_, int nPa, const float* __restrict__ addA, long adsA,
    const float* __restrict__ gva, const float* __restrict__ bva, float* __restrict__ oa,
    const float* __restrict__ Pb_, int nPb, const float* __restrict__ addB, long adsB,
    const float* __restrict__ gvb, const float* __restrict__ bvb, float* __restrict__ ob) {
  int which = blockIdx.x >> 4, r = blockIdx.x & 15, c = threadIdx.x;
  const float* P = which ? Pb_ : Pa_;
  int nP = which ? nPb : nPa;
  const float* add = which ? addB : addA;
  long ads = which ? adsB : adsA;
  const float* gv = which ? gvb : gva;
  const float* bv = which ? bvb : bva;
  float* o = which ? ob : oa;
  __shared__ float red[18];
  float v = add ? add[(size_t)r * ads + c] : 0.0f;
  for (int ks = 0; ks < nP; ks++) v += P[((size_t)ks * 16 + r) * HID + c];
  float m = block_sum(v, red, 16) * (1.0f / (float)HID);
  float d = v - m;
  float var = block_sum(d * d, red, 16) * (1.0f / (float)HID);
  float rs = 1.0f / sqrtf(var + 1e-3f);
  float y = d * rs * gv[c] + bv[c];
  float s = 1.0f / (1.0f + expf(-y));
  o[r * HID + c] = y * s;
}

// ---------------- init sample (mode) ----------------
__global__ __launch_bounds__(1024) void k_samp_init(
    const float* __restrict__ P, int nP, const float* __restrict__ bb,
    float* __restrict__ st) {
  int r = blockIdx.x, c = threadIdx.x;
  float acc = bb[c];
  for (int ks = 0; ks < nP; ks++) acc += P[((size_t)ks * 16 + r) * SD + c];
  int d = c & 31;
  float mx = acc;
#pragma unroll
  for (int m = 16; m >= 1; m >>= 1) mx = fmaxf(mx, __shfl_xor(mx, m, 32));
  float e = expf(acc - mx);
  float se = e;
#pragma unroll
  for (int m = 16; m >= 1; m >>= 1) se += __shfl_xor(se, m, 32);
  float p = 0.99f * (e / se) + 3.125e-4f;
  float by = p; int bi = d;
#pragma unroll
  for (int m = 16; m >= 1; m >>= 1) {
    float oy = __shfl_xor(by, m, 32);
    int oi = __shfl_xor(bi, m, 32);
    if (oy > by || (oy == by && oi < bi)) { by = oy; bi = oi; }
  }
  float oh = (d == bi) ? 1.0f : 0.0f;
  st[r * SD + c] = (oh + p) - p;
}

// ---------------- tiled GEMM (OE precompute): out[M x 1024] = A @ Bw ----------
__global__ __launch_bounds__(256) void k_mm(const float* __restrict__ A, long lda,
                                            const float* __restrict__ Bw, int K,
                                            float* __restrict__ out, long ldo) {
  __shared__ float As[32][68];
  __shared__ float Bs[32][68];
  const int tid = threadIdx.x;
  const int tx = tid & 15, ty = tid >> 4;
  const int row0 = blockIdx.y * 64, col0 = blockIdx.x * 64;
  const int ar = tid >> 2, ak = (tid & 3) * 8;
  const int bk = tid >> 4, bc = (tid & 15) * 4;
  float acc[4][4] = {};
  const float* ap = A + (size_t)(row0 + ar) * lda + ak;
  const float* bp = Bw + (size_t)bk * HID + col0 + bc;
  for (int k0 = 0; k0 < K; k0 += 32) {
    float4 a0 = *(const float4*)(ap + k0);
    float4 a1 = *(const float4*)(ap + k0 + 4);
    float4 b0 = *(const float4*)(bp + (size_t)k0 * HID);
    float4 b1 = *(const float4*)(bp + (size_t)(k0 + 16) * HID);
    __syncthreads();
    As[ak + 0][ar] = a0.x; As[ak + 1][ar] = a0.y; As[ak + 2][ar] = a0.z; As[ak + 3][ar] = a0.w;
    As[ak + 4][ar] = a1.x; As[ak + 5][ar] = a1.y; As[ak + 6][ar] = a1.z; As[ak + 7][ar] = a1.w;
    *(float4*)&Bs[bk][bc] = b0;
    *(float4*)&Bs[bk + 16][bc] = b1;
    __syncthreads();
#pragma unroll
    for (int kk = 0; kk < 32; kk++) {
      float4 av = *(const float4*)&As[kk][ty * 4];
      float4 bv = *(const float4*)&Bs[kk][tx * 4];
      acc[0][0] += av.x * bv.x; acc[0][1] += av.x * bv.y; acc[0][2] += av.x * bv.z; acc[0][3] += av.x * bv.w;
      acc[1][0] += av.y * bv.x; acc[1][1] += av.y * bv.y; acc[1][2] += av.y * bv.z; acc[1][3] += av.y * bv.w;
      acc[2][0] += av.z * bv.x; acc[2][1] += av.z * bv.y; acc[2][2] += av.z * bv.z; acc[2][3] += av.z * bv.w;
      acc[3][0] += av.w * bv.x; acc[3][1] += av.w * bv.y; acc[3][2] += av.w * bv.z; acc[3][3] += av.w * bv.w;
    }
  }
#pragma unroll
  for (int i = 0; i < 4; i++) {
    int col = col0 + tx * 4;
    float4 o;
    o.x = acc[i][0]; o.y = acc[i][1]; o.z = acc[i][2]; o.w = acc[i][3];
    *(float4*)(out + (size_t)(row0 + ty * 4 + i) * ldo + col) = o;
  }
}

// ---------------- GRU stage-1 reduce: sum splits + (sum, sumsq) per chunk ----------
__global__ __launch_bounds__(256) void k_red(const float* __restrict__ P, int nP,
                                             float* __restrict__ S,
                                             float* __restrict__ red_s, float* __restrict__ red_q) {
  int chunk = blockIdx.x, r = blockIdx.y;
  int c = chunk * 1024 + threadIdx.x * 4;
  float4 s = {0, 0, 0, 0};
  for (int ks = 0; ks < nP; ks++) {
    float4 v = *(const float4*)(P + ((size_t)ks * 16 + r) * (3 * DET) + c);
    s.x += v.x; s.y += v.y; s.z += v.z; s.w += v.w;
  }
  *(float4*)(S + (size_t)r * (3 * DET) + c) = s;
  float sx = (s.x + s.y) + (s.z + s.w);
  float sq = (s.x * s.x + s.y * s.y) + (s.z * s.z + s.w * s.w);
  __shared__ float rbuf[8];
#pragma unroll
  for (int m = 32; m >= 1; m >>= 1) { sx += __shfl_xor(sx, m, 64); sq += __shfl_xor(sq, m, 64); }
  int wid = threadIdx.x >> 6;
  if ((threadIdx.x & 63) == 0) { rbuf[wid] = sx; rbuf[4 + wid] = sq; }
  __syncthreads();
  if (threadIdx.x == 0) {
    red_s[r * 12 + chunk] = (rbuf[0] + rbuf[1]) + (rbuf[2] + rbuf[3]);
    red_q[r * 12 + chunk] = (rbuf[4] + rbuf[5]) + (rbuf[6] + rbuf[7]);
  }
}

// ---- obs+prior GEMM with fused GRU-gate recompute (z-batched, per 128-col K-slice) ----
__global__ __launch_bounds__(256) void k_obsg2(
    const float* __restrict__ Sg, const float* __restrict__ red_s, const float* __restrict__ red_q,
    const float* __restrict__ gg, const float* __restrict__ bg,
    const float* __restrict__ din_cur, float* __restrict__ din_next,
    const float* __restrict__ init_deter, const float* __restrict__ isf, int t,
    const float* __restrict__ W0, float* __restrict__ P0,
    const float* __restrict__ W1p, float* __restrict__ P1p,
    float* __restrict__ out) {
  const int tid = threadIdx.x;
  const int tile = blockIdx.x;
  const int split = blockIdx.y;
  const int z = blockIdx.z;
  const float* W = z ? W1p : W0;
  float* P = z ? P1p : P0;
  const int c0 = tile * 512 + tid * 2;
  const int j0 = split * 128;
  __shared__ float dn_s[16][128];
  __shared__ float mvf[16][3];
  if (tid < 16) {
    int r = tid;
    float s = 0.f, q = 0.f;
    for (int k2 = 0; k2 < 12; k2++) { s += red_s[r * 12 + k2]; q += red_q[r * 12 + k2]; }
    float m = s * (1.0f / (float)(3 * DET));
    float var = q * (1.0f / (float)(3 * DET)) - m * m;
    mvf[r][0] = m; mvf[r][1] = 1.0f / sqrtf(var + 1e-3f);
    mvf[r][2] = (t + 1 < T_STEPS) ? isf[r * T_STEPS + t + 1] : 0.0f;
  }
  __syncthreads();
  for (int e = tid; e < 16 * 128; e += 256) {
    int r = e >> 7, jj = e & 127;
    int j = j0 + jj;
    float m = mvf[r][0], rs = mvf[r][1];
    const float* Sr = Sg + (size_t)r * (3 * DET);
    float lr = (Sr[j] - m) * rs * gg[j] + bg[j];
    float lc = (Sr[j + DET] - m) * rs * gg[j + DET] + bg[j + DET];
    float lu = (Sr[j + 2 * DET] - m) * rs * gg[j + 2 * DET] + bg[j + 2 * DET];
    float rr = 1.0f / (1.0f + expf(-lr));
    float cd = tanhf(rr * lc);
    float uu = 1.0f / (1.0f + expf(-(lu - 1.0f)));
    float dn = uu * cd + (1.0f - uu) * din_cur[r * DET + j];
    dn_s[r][jj] = dn;
    if (z == 0 && tile == 0) {
      out[(size_t)(r * T_STEPS + t) * OUT_C + 1024 + j] = dn;
      float ft = mvf[r][2];
      din_next[r * DET + j] = dn * (1.0f - ft) + init_deter[j] * ft;
    }
  }
  __syncthreads();
  float acc[16][2];
#pragma unroll
  for (int r = 0; r < 16; r++) { acc[r][0] = 0.f; acc[r][1] = 0.f; }
  for (int kb = 0; kb < 128; kb += 64) {
    const float* wp = W + (size_t)(j0 + kb) * HID + c0;
#pragma unroll 4
    for (int kk = 0; kk < 64; kk++) {
      f2v w = NTL((const f2v*)wp);
      wp += HID;
#pragma unroll
      for (int r = 0; r < 16; r++) {
        float iv = dn_s[r][kb + kk];
        acc[r][0] += iv * w[0]; acc[r][1] += iv * w[1];
      }
    }
  }
#pragma unroll
  for (int r = 0; r < 16; r++)
    *(f2v*)(P + ((size_t)split * 16 + r) * HID + c0) = f2v{acc[r][0], acc[r][1]};
}

// ---------------- batched sample (epilogue t=63): prior + post ----------------
__global__ __launch_bounds__(1024) void k_samp2(
    const float* __restrict__ P0, const float* __restrict__ bb0,
    const float* __restrict__ gum0, long gs0,
    const float* __restrict__ P1, const float* __restrict__ bb1,
    const float* __restrict__ gum1, long gs1,
    float* __restrict__ out, int t, int nP,
    const float* __restrict__ isf, const float* __restrict__ pa,
    float* __restrict__ stoch_in, float* __restrict__ a_eff,
    const float* __restrict__ init_stoch) {
  int which = blockIdx.x >> 4, r = blockIdx.x & 15, c = threadIdx.x;
  const float* P = which ? P1 : P0;
  const float* bbv = which ? bb1 : bb0;
  const float* gum = which ? gum1 : gum0;
  long gs = which ? gs1 : gs0;
  float acc = bbv[c];
  for (int ks = 0; ks < nP; ks++) acc += P[((size_t)ks * 16 + r) * SD + c];
  int d = c & 31;
  float mx = acc;
#pragma unroll
  for (int m = 16; m >= 1; m >>= 1) mx = fmaxf(mx, __shfl_xor(mx, m, 32));
  float e = expf(acc - mx);
  float se = e;
#pragma unroll
  for (int m = 16; m >= 1; m >>= 1) se += __shfl_xor(se, m, 32);
  float p = 0.99f * (e / se) + 3.125e-4f;
  float y = logf(p) + gum[(long)r * gs + c];
  float by = y; int bi = d;
#pragma unroll
  for (int m = 16; m >= 1; m >>= 1) {
    float oy = __shfl_xor(by, m, 32);
    int oi = __shfl_xor(bi, m, 32);
    if (oy > by || (oy == by && oi < bi)) { by = oy; bi = oi; }
  }
  float oh = (d == bi) ? 1.0f : 0.0f;
  float outv = (oh + p) - p;
  float* ob = out + (size_t)t * OUT_C + (size_t)r * OUT_RSTRIDE;
  if (which) {
    ob[c] = outv;
    ob[5120 + c] = acc;
    float fn = (t + 1 < T_STEPS) ? isf[r * T_STEPS + t + 1] : 0.0f;
    stoch_in[r * SD + c] = outv * (1.0f - fn) + init_stoch[r * SD + c] * fn;
    if (c < A_DIM) {
      float a = (t + 1 < T_STEPS) ? pa[(r * T_STEPS + t + 1) * A_DIM + c] : 0.0f;
      a = a * (1.0f / fmaxf(fabsf(a), 1.0f));
      a_eff[r * 8 + c] = a * (1.0f - fn);
    }
  } else {
    ob[6144 + c] = outv;
    ob[7168 + c] = acc;
  }
}

// ---------------- host ----------------
static inline GemmArgs mkargs(const float* A0, long sA0, int cA0,
                              const float* A1, long sA1,
                              const float* W, int N, int Ktot, int KS, int nsplit, float* P) {
  GemmArgs g; g.A0 = A0; g.sA0 = sA0; g.cA0 = cA0; g.A1 = A1; g.sA1 = sA1;
  g.W = W; g.N = N; g.Ktot = Ktot; g.KS = KS; g.nsplit = nsplit; g.P = P;
  return g;
}

extern "C" void kernel_launch(void* const* d_in, const int* in_sizes, int n_in,
                              void* d_out, int out_size, void* d_ws, size_t ws_size,
                              hipStream_t stream) {
  const float* embed  = (const float*)d_in[0];
  const float* pa     = (const float*)d_in[1];
  const float* isf    = (const float*)d_in[2];
  const float* gprior = (const float*)d_in[3];
  const float* gpost  = (const float*)d_in[4];
  const float* w_init = (const float*)d_in[5];
  const float* W1  = (const float*)d_in[6];
  const float* g1  = (const float*)d_in[7];
  const float* b1  = (const float*)d_in[8];
  const float* Wg  = (const float*)d_in[9];
  const float* gg  = (const float*)d_in[10];
  const float* bg  = (const float*)d_in[11];
  const float* W2a = (const float*)d_in[12];
  const float* g2  = (const float*)d_in[13];
  const float* b2  = (const float*)d_in[14];
  const float* W2b = (const float*)d_in[15];
  const float* bb2 = (const float*)d_in[16];
  const float* Wo  = (const float*)d_in[17];
  const float* go  = (const float*)d_in[18];
  const float* bo  = (const float*)d_in[19];
  const float* Wob = (const float*)d_in[20];
  const float* bbo = (const float*)d_in[21];
  float* out = (float*)d_out;
  float* ws  = (float*)d_ws;

  // workspace (floats): partial buffers aliased into the Pg arena
  float* Pg    = ws;                    // 20*16*12288 = 3,932,160
  float* Pimg1 = ws;                    // 278,528   (alias, dead before gruG)
  float* Pa    = ws + 278528;           // 524,288
  float* Pb    = ws + 802816;           // 524,288
  float* Ps0   = ws + 1327104;          // 262,144
  float* Ps1   = ws + 1589248;          // 262,144
  float* Sg    = ws + 3932160;          // 196,608
  float* red_s = Sg + 196608;           // 192
  float* red_q = red_s + 192;           // 192 (+pad)
  float* st_   = red_s + 512;
  float* init_stoch = st_;              // 16,384
  float* init_deter = st_ + 16384;      // 4,096
  float* stoch_in   = st_ + 20480;      // 16,384
  float* din0       = st_ + 36864;      // 65,536
  float* din1       = st_ + 102400;     // 65,536
  float* a_eff      = st_ + 167936;     // 128
  float* x          = st_ + 168064;     // 16,384
  float* h          = st_ + 184448;     // 16,384
  float* h2         = st_ + 200832;     // 16,384

  GemmArgs Z = mkargs(nullptr, 0, 0, nullptr, 0, nullptr, 1, 0, 64, 0, nullptr);

  // ---- OE precompute ----
  k_mm<<<dim3(16, 16), 256, 0, stream>>>(embed, E_DIM, Wo, E_DIM, out + 5120, OUT_C);

  // ---- init chain ----
  k_tanh<<<4, 1024, 0, stream>>>(w_init, init_deter);
  k_gemm<true><<<dim3(1, 32, 1), 256, 0, stream>>>(
      mkargs(init_deter, 0, DET, nullptr, 0, W2a, HID, DET, 128, 32, Pb), Z);
  k_fin2<<<16, 1024, 0, stream>>>(Pb, 32, nullptr, 0, g2, b2, x,
                                  Pb, 32, nullptr, 0, g2, b2, x);
  k_gemm<true><<<dim3(1, 16, 1), 256, 0, stream>>>(
      mkargs(x, HID, HID, nullptr, 0, W2b, SD, HID, 64, 16, Ps1), Z);
  k_samp_init<<<16, 1024, 0, stream>>>(Ps1, 16, bb2, init_stoch);

  // ---- t=0 prep ----
  k_prep<<<16, 256, 0, stream>>>(isf, pa, 0, init_stoch, init_deter, 0,
                                 init_stoch, init_deter, stoch_in, din0, a_eff);

  const float* Wo2 = Wo + (size_t)E_DIM * HID;
  for (int t = 0; t < T_STEPS; t++) {
    float* din_cur  = (t & 1) ? din1 : din0;
    float* din_next = (t & 1) ? din0 : din1;
    int tprev = t - 1;
    // 1) img1 GEMM fused with prev-step post/prior sample recompute
    k_img1s<<<dim3(1, 33), 256, 0, stream>>>(
        stoch_in, a_eff, tprev >= 0 ? Ps1 : nullptr, tprev >= 0 ? Ps0 : nullptr,
        bbo, bb2,
        gpost + (size_t)(tprev >= 0 ? tprev : 0) * SD,
        gprior + (size_t)(tprev >= 0 ? tprev : 0) * SD,
        out, tprev, isf, pa, t, init_stoch, W1, Pimg1);
    // 2) img1 finish -> x
    k_fin2<<<16, 1024, 0, stream>>>(Pimg1, 17, nullptr, 0, g1, b1, x,
                                    Pimg1, 17, nullptr, 0, g1, b1, x);
    // 3) GRU GEMM (Wg L3-cacheable)
    k_gemm<false><<<dim3(12, 20, 1), 256, 0, stream>>>(
        mkargs(x, HID, HID, din_cur, DET, Wg, 3 * DET, HID + DET, 256, 20, Pg), Z);
    // 4) reduce -> Sg + chunk stats
    k_red<<<dim3(12, 16), 256, 0, stream>>>(Pg, 20, Sg, red_s, red_q);
    // 5) obs + prior GEMMs with fused gate recompute
    k_obsg2<<<dim3(2, 32, 2), 256, 0, stream>>>(Sg, red_s, red_q, gg, bg, din_cur, din_next,
                                                init_deter, isf, t, Wo2, Pb, W2a, Pa, out);
    // 6) batched finish: prior h || obs h2 (+OE)
    k_fin2<<<32, 1024, 0, stream>>>(Pa, 32, nullptr, 0, g2, b2, h,
                                    Pb, 32, out + (size_t)t * OUT_C + 5120, OUT_RSTRIDE,
                                    go, bo, h2);
    // 7) batched sample GEMMs: h@W2b -> Ps0 || h2@Wob -> Ps1
    k_gemm<true><<<dim3(1, 16, 2), 256, 0, stream>>>(
        mkargs(h, HID, HID, nullptr, 0, W2b, SD, HID, 64, 16, Ps0),
        mkargs(h2, HID, HID, nullptr, 0, Wob, SD, HID, 64, 16, Ps1));
  }

  // ---- epilogue: samples for t = 63 ----
  k_samp2<<<32, 1024, 0, stream>>>(
      Ps0, bb2, gprior + (size_t)(T_STEPS - 1) * SD, (long)T_STEPS * SD,
      Ps1, bbo, gpost + (size_t)(T_STEPS - 1) * SD, (long)T_STEPS * SD,
      out, T_STEPS - 1, 16, isf, pa, stoch_in, a_eff, init_stoch);
}